// Round 1
// baseline (46700.848 us; speedup 1.0000x reference)
//
#include <hip/hip_runtime.h>

typedef short v8s __attribute__((ext_vector_type(8)));
typedef float f32x4 __attribute__((ext_vector_type(4)));
typedef unsigned short u16;

static constexpr int kB = 64;    // batch
static constexpr int kH = 1024;  // hidden
static constexpr int kD = 128;   // input dim
static constexpr int kL = 3;     // layers
static constexpr int NBLK = 128; // proven cooperative grid size
static constexpr int NTHR = 512; // 8 waves -> 8-way K-split
static constexpr int NFLAG = 8192;  // barrier flag words (128 lines)
static constexpr int XS = 136;   // x LDS row stride (u16): 272B row -> 2-way max aliasing

__device__ __forceinline__ u16 f2b(float f) {
  union { float f; unsigned u; } v; v.f = f;
  unsigned r = v.u + 0x7fffu + ((v.u >> 16) & 1u);
  return (u16)(r >> 16);
}

__device__ __forceinline__ float sigm(float x) { return 1.f / (1.f + expf(-x)); }

// Write-through stores: land at LLC (coherent point), leave no dirty L2 lines.
__device__ __forceinline__ void st32(float* p, float v) {
  asm volatile("global_store_dword %0, %1, off sc0 sc1" :: "v"(p), "v"(v) : "memory");
}
__device__ __forceinline__ void st32u(unsigned* p, unsigned v) {
  asm volatile("global_store_dword %0, %1, off sc0 sc1" :: "v"(p), "v"(v) : "memory");
}
__device__ __forceinline__ void st128(u16* p, v8s v) {
  asm volatile("global_store_dwordx4 %0, %1, off sc0 sc1" :: "v"(p), "v"(v) : "memory");
}

struct Params {
  const float *x, *h0, *c0;
  const float *Wi0, *Wh0, *bi0, *bh0;
  const float *Wi1, *Wh1, *bi1, *bh1;
  const float *Wi2, *Wh2, *bi2, *bh2;
  const float *Wfc, *bfc;
  float *out;
  u16 *wb0i, *wb0h, *wb1i, *wb1h, *wb2i, *wb2h, *wbfc;
  u16 *xb, *hA, *hB;
  float *b0, *b1, *b2, *bfcs;
  unsigned *bflags;  // flags[b*32]: one cache line per block
  int P, T;
};

// Single-hop serialization-free grid barrier.
// Arrival: per-wave vmcnt drain -> block syncthreads -> thread0 stores its
// own generation flag (own cache line, parallel across blocks, no RMW).
// Wait: EVERY block polls all 128 flags directly with threads 0..127
// (relaxed agent loads -- same mechanism block0 used before; removes the
// gen-publish second hop). Exit: ACQUIRE load (buffer_inv) kills stale
// L1/L2 lines before the next layer's h-reads.
__device__ __forceinline__ void gbar(unsigned* flags, unsigned& g, int bid) {
  const unsigned tgt = g + 1u;
  asm volatile("s_waitcnt vmcnt(0)" ::: "memory");  // drain this wave's stores
  __syncthreads();                                  // all waves drained
  if (threadIdx.x == 0) st32u(flags + bid * 32, tgt);
  const int i = threadIdx.x;
  unsigned* fp = flags + i * 32;
  for (;;) {
    unsigned v = (i < NBLK)
        ? __hip_atomic_load(fp, __ATOMIC_RELAXED, __HIP_MEMORY_SCOPE_AGENT)
        : tgt;
    if (__syncthreads_and((int)(v >= tgt))) break;
    __builtin_amdgcn_s_sleep(1);
  }
  (void)__hip_atomic_load(flags + bid * 32, __ATOMIC_ACQUIRE,
                          __HIP_MEMORY_SCOPE_AGENT);
  g = tgt;
}

// ---------------- init: fp32 -> bf16 conversions, bias sums, state init ----
__global__ void init_kernel(Params p) {
  long gid = (long)blockIdx.x * blockDim.x + threadIdx.x;
  long stride = (long)gridDim.x * blockDim.x;
  const long nw0i = 4096L * kD, nwh = 4096L * kH, nfc = (long)kD * kH;
  for (long i = gid; i < nw0i; i += stride) p.wb0i[i] = f2b(p.Wi0[i]);
  for (long i = gid; i < nwh; i += stride) {
    p.wb0h[i] = f2b(p.Wh0[i]);
    p.wb1i[i] = f2b(p.Wi1[i]);
    p.wb1h[i] = f2b(p.Wh1[i]);
    p.wb2i[i] = f2b(p.Wi2[i]);
    p.wb2h[i] = f2b(p.Wh2[i]);
  }
  for (long i = gid; i < nfc; i += stride) p.wbfc[i] = f2b(p.Wfc[i]);
  for (long i = gid; i < 4096; i += stride) {
    p.b0[i] = p.bi0[i] + p.bh0[i];
    p.b1[i] = p.bi1[i] + p.bh1[i];
    p.b2[i] = p.bi2[i] + p.bh2[i];
  }
  for (long i = gid; i < kD; i += stride) p.bfcs[i] = p.bfc[i];
  for (long i = gid; i < NFLAG; i += stride) p.bflags[i] = 0u;  // barrier state
  long nx = (long)p.P * kB * kD;
  for (long i = gid; i < nx; i += stride) {
    p.xb[i] = f2b(p.x[i]);
    p.out[i] = p.x[i];  // teacher-forced rows are exact copies
  }
  long nh = (long)kL * kB * kH;
  for (long i = gid; i < nh; i += stride) p.hA[i] = f2b(p.h0[i]);
}

// ---------------- persistent RNN: weights live in VGPRs, 8-way K-split ----
// 128 blocks x 512 thr. Block owns 8 hidden units [8b,8b+8) x 4 gates = 32
// gate-rows/layer as TWO n-tiles: tile j = gates {2j,2j+1}; col c -> gate
// 2j+(c>>3), unit c&7. Wave w (0..7) owns 1/8 of K; partials sum via LDS.
// MFMA 16x16x32: A row=lane&15(m), k=(lane>>4)*8+j; D col=lane&15, row=kq*4+r.
// Gen-phase FC is computed REDUNDANTLY by every block at the start of the
// L0 phase (from h2 of the previous step, already published) -> 3 barriers
// per step instead of 4, no curx broadcast buffer.
__global__ void __launch_bounds__(NTHR) rnn_kernel(Params p) {
  const int tid = threadIdx.x, bid = blockIdx.x;
  const int lane = tid & 63, w = tid >> 6;  // 8 waves
  const int colc = lane & 15, kq = lane >> 4;
  const int aoff = kq * 8;
  const int u7 = colc & 7, gh = colc >> 3;
  const long wr0 = (long)gh * kH + bid * 8 + u7;        // gate-rows 0/1 tile
  const long wr1 = (long)(2 + gh) * kH + bid * 8 + u7;  // gate-rows 2/3 tile
  unsigned bg = 0;

  // ---- one-time weight preload: 42 tiles = 168 VGPRs/wave ----
  const int cnt0 = (w < 4) ? 5 : 4;
  const int off0 = (w < 4) ? w * 5 : 20 + (w - 4) * 4;
  v8s w0[2][5], w1[2][8], w2[2][8];
#pragma unroll
  for (int i = 0; i < 5; ++i)
    if (i < cnt0) {
      int gt = off0 + i;
      if (gt < 4) {
        w0[0][i] = *(const v8s*)(p.wb0i + wr0 * kD + gt * 32 + aoff);
        w0[1][i] = *(const v8s*)(p.wb0i + wr1 * kD + gt * 32 + aoff);
      } else {
        w0[0][i] = *(const v8s*)(p.wb0h + wr0 * kH + (gt - 4) * 32 + aoff);
        w0[1][i] = *(const v8s*)(p.wb0h + wr1 * kH + (gt - 4) * 32 + aoff);
      }
    }
#pragma unroll
  for (int i = 0; i < 8; ++i) {
    int gt = w * 8 + i;
    const u16* s1 = (gt < 32) ? p.wb1i : p.wb1h;
    const u16* s2 = (gt < 32) ? p.wb2i : p.wb2h;
    int k = (gt & 31) * 32 + aoff;
    w1[0][i] = *(const v8s*)(s1 + wr0 * kH + k);
    w1[1][i] = *(const v8s*)(s1 + wr1 * kH + k);
    w2[0][i] = *(const v8s*)(s2 + wr0 * kH + k);
    w2[1][i] = *(const v8s*)(s2 + wr1 * kH + k);
  }

  // ---- per-thread cell state: 1 (batch, unit) cell per layer ----
  const int em = tid >> 3, eu = tid & 7;
  const int ehid = bid * 8 + eu;
  float cst[kL], brg[kL][4];
#pragma unroll
  for (int l = 0; l < kL; ++l)
    cst[l] = p.c0[(long)l * kB * kH + (long)em * kH + ehid];
  {
    const float* bp[3] = {p.b0, p.b1, p.b2};
#pragma unroll
    for (int l = 0; l < 3; ++l)
#pragma unroll
      for (int gg = 0; gg < 4; ++gg) brg[l][gg] = bp[l][gg * kH + ehid];
  }

  __shared__ float lg[8][64][18];  // stride 18: <=2-way bank aliasing
  __shared__ u16 xsh[64 * XS];     // current-step input x(t), bf16
  __shared__ u16 hsh[64][8];       // block's h-slice staging for coalesced store
  const int T = p.T, P = p.P;
  const f32x4 z4 = {0.f, 0.f, 0.f, 0.f};
  const float bfc_r = p.bfcs[w * 16 + colc];          // per-thread FC bias
  const u16* wfc_r = p.wbfc + (long)(w * 16 + colc) * kH + aoff;  // FC B row

  auto epilogue = [&](int l, f32x4(&acc)[2][4], u16* hOut) {
    float pre[4];
#pragma unroll
    for (int mt = 0; mt < 4; ++mt)
#pragma unroll
      for (int r = 0; r < 4; ++r) lg[w][mt * 16 + kq * 4 + r][colc] = acc[0][mt][r];
    __syncthreads();
    {
      float s0 = 0.f, s1 = 0.f;
#pragma unroll
      for (int ww = 0; ww < 8; ++ww) {
        s0 += lg[ww][em][eu];
        s1 += lg[ww][em][8 + eu];
      }
      pre[0] = s0;
      pre[1] = s1;
    }
    __syncthreads();
#pragma unroll
    for (int mt = 0; mt < 4; ++mt)
#pragma unroll
      for (int r = 0; r < 4; ++r) lg[w][mt * 16 + kq * 4 + r][colc] = acc[1][mt][r];
    __syncthreads();
    {
      float s0 = 0.f, s1 = 0.f;
#pragma unroll
      for (int ww = 0; ww < 8; ++ww) {
        s0 += lg[ww][em][eu];
        s1 += lg[ww][em][8 + eu];
      }
      pre[2] = s0;
      pre[3] = s1;
    }
    float iv = pre[0] + brg[l][0], fv = pre[1] + brg[l][1];
    float gv = pre[2] + brg[l][2], ov = pre[3] + brg[l][3];
    float cn = sigm(fv) * cst[l] + sigm(iv) * tanhf(gv);
    cst[l] = cn;
    hsh[em][eu] = f2b(sigm(ov) * tanhf(cn));
    __syncthreads();  // hsh complete
    // 64x16B coalesced write-through publish (vs 512x2B): faster vmcnt drain
    if (tid < 64)
      st128(hOut + (long)tid * kH + bid * 8, *(const v8s*)&hsh[tid][0]);
  };

  for (int t = 0; t < T - 1; ++t) {
    const u16* hOld = (t & 1) ? p.hB : p.hA;
    u16* hNew = (t & 1) ? p.hA : p.hB;

    // ===== stage x(t) into LDS: teacher-forced copy, or redundant FC =====
    if (t < P) {
      const u16* xg = p.xb + (long)t * kB * kD;
      for (int j = tid; j < (kB * kD) / 8; j += NTHR) {
        int bb = j >> 4, k8 = (j & 15) * 8;
        *(v8s*)(xsh + bb * XS + k8) = *(const v8s*)(xg + bb * kD + k8);
      }
    } else {
      // x(t) = sigmoid(h2(t-1) @ Wfc^T + bfc); h2(t-1) = layer-2 slab of hOld,
      // published by barrier 3 of the previous iteration. Wave w owns n-tile w
      // (out dims w*16..w*16+15), m-tiles 0..3, full K=1024. 128 MFMA/wave.
      const u16* ap = hOld + 2L * kB * kH + (long)colc * kH + aoff;
      f32x4 fa[4] = {z4, z4, z4, z4};
#pragma unroll 2
      for (int kk = 0; kk < 32; ++kk) {
        v8s b = *(const v8s*)(wfc_r + kk * 32);
#pragma unroll
        for (int mt = 0; mt < 4; ++mt) {
          v8s a = *(const v8s*)(ap + mt * 16 * kH + kk * 32);
          fa[mt] = __builtin_amdgcn_mfma_f32_16x16x32_bf16(a, b, fa[mt], 0, 0, 0);
        }
      }
      float* orow = p.out + (long)t * (kB * kD);
#pragma unroll
      for (int mt = 0; mt < 4; ++mt)
#pragma unroll
        for (int r = 0; r < 4; ++r) {
          float val = sigm(fa[mt][r] + bfc_r);
          int bb = mt * 16 + kq * 4 + r, d = w * 16 + colc;
          xsh[bb * XS + d] = f2b(val);
          if (bid == 0) st32(orow + (long)bb * kD + d, val);  // emit out[t]
        }
    }
    __syncthreads();  // xsh ready

    // ===== layer 0 (x-part from LDS, h-part from hOld) =====
    {
      f32x4 acc[2][4] = {z4, z4, z4, z4, z4, z4, z4, z4};
#pragma unroll
      for (int i = 0; i < 5; ++i)
        if (i < cnt0) {
          int gt = off0 + i;
          if (gt < 4) {
            int k = gt * 32 + aoff;
#pragma unroll
            for (int mt = 0; mt < 4; ++mt) {
              v8s a = *(const v8s*)(xsh + (mt * 16 + colc) * XS + k);
              acc[0][mt] = __builtin_amdgcn_mfma_f32_16x16x32_bf16(a, w0[0][i], acc[0][mt], 0, 0, 0);
              acc[1][mt] = __builtin_amdgcn_mfma_f32_16x16x32_bf16(a, w0[1][i], acc[1][mt], 0, 0, 0);
            }
          } else {
            int k = (gt - 4) * 32 + aoff;
#pragma unroll
            for (int mt = 0; mt < 4; ++mt) {
              v8s a = *(const v8s*)(hOld + (long)(mt * 16 + colc) * kH + k);
              acc[0][mt] = __builtin_amdgcn_mfma_f32_16x16x32_bf16(a, w0[0][i], acc[0][mt], 0, 0, 0);
              acc[1][mt] = __builtin_amdgcn_mfma_f32_16x16x32_bf16(a, w0[1][i], acc[1][mt], 0, 0, 0);
            }
          }
        }
      epilogue(0, acc, hNew);
    }
    gbar(p.bflags, bg, bid);

    // ===== layer 1 (x-part = h_l0 new, h-part = h_l1 old) =====
    {
      f32x4 acc[2][4] = {z4, z4, z4, z4, z4, z4, z4, z4};
      const u16* Ax = hNew;
      const u16* Ah = hOld + (long)kB * kH;
#pragma unroll
      for (int i = 0; i < 8; ++i) {
        int gt = w * 8 + i;
        const u16* Ab = (gt < 32) ? Ax : Ah;
        int k = (gt & 31) * 32 + aoff;
#pragma unroll
        for (int mt = 0; mt < 4; ++mt) {
          v8s a = *(const v8s*)(Ab + (long)(mt * 16 + colc) * kH + k);
          acc[0][mt] = __builtin_amdgcn_mfma_f32_16x16x32_bf16(a, w1[0][i], acc[0][mt], 0, 0, 0);
          acc[1][mt] = __builtin_amdgcn_mfma_f32_16x16x32_bf16(a, w1[1][i], acc[1][mt], 0, 0, 0);
        }
      }
      epilogue(1, acc, hNew + (long)kB * kH);
    }
    gbar(p.bflags, bg, bid);

    // ===== layer 2 =====
    {
      f32x4 acc[2][4] = {z4, z4, z4, z4, z4, z4, z4, z4};
      const u16* Ax = hNew + (long)kB * kH;
      const u16* Ah = hOld + 2L * kB * kH;
#pragma unroll
      for (int i = 0; i < 8; ++i) {
        int gt = w * 8 + i;
        const u16* Ab = (gt < 32) ? Ax : Ah;
        int k = (gt & 31) * 32 + aoff;
#pragma unroll
        for (int mt = 0; mt < 4; ++mt) {
          v8s a = *(const v8s*)(Ab + (long)(mt * 16 + colc) * kH + k);
          acc[0][mt] = __builtin_amdgcn_mfma_f32_16x16x32_bf16(a, w2[0][i], acc[0][mt], 0, 0, 0);
          acc[1][mt] = __builtin_amdgcn_mfma_f32_16x16x32_bf16(a, w2[1][i], acc[1][mt], 0, 0, 0);
        }
      }
      epilogue(2, acc, hNew + 2L * kB * kH);
    }
    gbar(p.bflags, bg, bid);
  }

  // ===== final emitted row out[T-1]: FC from h2(T-2), block 0 only =====
  if (bid == 0 && T - 1 >= P && T >= 2) {
    const u16* hL = ((T - 2) & 1) ? p.hA : p.hB;  // hNew of iteration T-2
    const u16* ap = hL + 2L * kB * kH + (long)colc * kH + aoff;
    f32x4 fa[4] = {z4, z4, z4, z4};
#pragma unroll 2
    for (int kk = 0; kk < 32; ++kk) {
      v8s b = *(const v8s*)(wfc_r + kk * 32);
#pragma unroll
      for (int mt = 0; mt < 4; ++mt) {
        v8s a = *(const v8s*)(ap + mt * 16 * kH + kk * 32);
        fa[mt] = __builtin_amdgcn_mfma_f32_16x16x32_bf16(a, b, fa[mt], 0, 0, 0);
      }
    }
    float* orow = p.out + (long)(T - 1) * (kB * kD);
#pragma unroll
    for (int mt = 0; mt < 4; ++mt)
#pragma unroll
      for (int r = 0; r < 4; ++r) {
        int bb = mt * 16 + kq * 4 + r, d = w * 16 + colc;
        st32(orow + (long)bb * kD + d, sigm(fa[mt][r] + bfc_r));
      }
  }
}

extern "C" void kernel_launch(void* const* d_in, const int* in_sizes, int n_in,
                              void* d_out, int out_size, void* d_ws, size_t ws_size,
                              hipStream_t stream) {
  Params p;
  p.x   = (const float*)d_in[0];
  p.h0  = (const float*)d_in[1];
  p.c0  = (const float*)d_in[2];
  p.Wi0 = (const float*)d_in[3];
  p.Wh0 = (const float*)d_in[4];
  p.bi0 = (const float*)d_in[5];
  p.bh0 = (const float*)d_in[6];
  p.Wi1 = (const float*)d_in[7];
  p.Wh1 = (const float*)d_in[8];
  p.bi1 = (const float*)d_in[9];
  p.bh1 = (const float*)d_in[10];
  p.Wi2 = (const float*)d_in[11];
  p.Wh2 = (const float*)d_in[12];
  p.bi2 = (const float*)d_in[13];
  p.bh2 = (const float*)d_in[14];
  p.Wfc = (const float*)d_in[15];
  p.bfc = (const float*)d_in[16];
  p.out = (float*)d_out;
  p.P = in_sizes[0] / (kB * kD);
  p.T = out_size / (kB * kD);

  char* w = (char*)d_ws;
  auto alloc = [&](size_t bytes) {
    char* r = w;
    w += (bytes + 255) & ~(size_t)255;
    return r;
  };
  p.wb0i = (u16*)alloc(4096L * kD * 2);
  p.wb0h = (u16*)alloc(4096L * kH * 2);
  p.wb1i = (u16*)alloc(4096L * kH * 2);
  p.wb1h = (u16*)alloc(4096L * kH * 2);
  p.wb2i = (u16*)alloc(4096L * kH * 2);
  p.wb2h = (u16*)alloc(4096L * kH * 2);
  p.wbfc = (u16*)alloc((long)kD * kH * 2);
  p.xb   = (u16*)alloc((long)p.P * kB * kD * 2);
  p.hA   = (u16*)alloc((long)kL * kB * kH * 2);
  p.hB   = (u16*)alloc((long)kL * kB * kH * 2);
  p.b0   = (float*)alloc(4096 * 4);
  p.b1   = (float*)alloc(4096 * 4);
  p.b2   = (float*)alloc(4096 * 4);
  p.bfcs = (float*)alloc(kD * 4);
  p.bflags = (unsigned*)alloc(NFLAG * 4);

  hipLaunchKernelGGL(init_kernel, dim3(512), dim3(256), 0, stream, p);
  void* args[] = { &p };
  hipLaunchCooperativeKernel((const void*)rnn_kernel, dim3(NBLK), dim3(NTHR),
                             args, 0, stream);
}

// Round 2
// 46648.895 us; speedup vs baseline: 1.0011x; 1.0011x over previous
//
#include <hip/hip_runtime.h>

typedef short v8s __attribute__((ext_vector_type(8)));
typedef float f32x4 __attribute__((ext_vector_type(4)));
typedef unsigned short u16;

static constexpr int kB = 64;    // batch
static constexpr int kH = 1024;  // hidden
static constexpr int kD = 128;   // input dim
static constexpr int kL = 3;     // layers
static constexpr int NBLK = 128; // proven cooperative grid size
static constexpr int NTHR = 512; // 8 waves -> 8-way K-split
static constexpr int NFLAG = 8192;  // barrier flag words (128 lines + gen)
static constexpr int XS = 136;   // x LDS row stride (u16): 272B row -> 2-way max aliasing

__device__ __forceinline__ u16 f2b(float f) {
  union { float f; unsigned u; } v; v.f = f;
  unsigned r = v.u + 0x7fffu + ((v.u >> 16) & 1u);
  return (u16)(r >> 16);
}

__device__ __forceinline__ float sigm(float x) { return 1.f / (1.f + expf(-x)); }

// Write-through stores: land at LLC (coherent point), leave no dirty L2 lines.
__device__ __forceinline__ void st32(float* p, float v) {
  asm volatile("global_store_dword %0, %1, off sc0 sc1" :: "v"(p), "v"(v) : "memory");
}
__device__ __forceinline__ void st32u(unsigned* p, unsigned v) {
  asm volatile("global_store_dword %0, %1, off sc0 sc1" :: "v"(p), "v"(v) : "memory");
}
__device__ __forceinline__ void st128(u16* p, v8s v) {
  asm volatile("global_store_dwordx4 %0, %1, off sc0 sc1" :: "v"(p), "v"(v) : "memory");
}

struct Params {
  const float *x, *h0, *c0;
  const float *Wi0, *Wh0, *bi0, *bh0;
  const float *Wi1, *Wh1, *bi1, *bh1;
  const float *Wi2, *Wh2, *bi2, *bh2;
  const float *Wfc, *bfc;
  float *out;
  u16 *wb0i, *wb0h, *wb1i, *wb1h, *wb2i, *wb2h, *wbfc;
  u16 *xb, *hA, *hB;
  float *b0, *b1, *b2, *bfcs;
  unsigned *bflags;  // flags[b*32] per-block lines; gen at [NBLK*32+32]
  int P, T;
};

// PROVEN two-hop grid barrier (round-0, 18.3us/phase).
// Arrival: per-wave vmcnt drain -> block syncthreads -> thread0 stores its
// own generation flag (own cache line, parallel across blocks, no RMW).
// Block 0: threads 0..127 poll the 128 flags in parallel; publish gen.
// Others: thread0 spins on gen. Exit: per-thread ACQUIRE load (buffer_inv)
// kills stale L1/L2 lines before the next layer's h-reads.
// (Round-1 single-hop variant — all blocks polling all flags — regressed
// 18.3 -> ~30us/phase: 128 readers per flag line at the LLC.)
__device__ __forceinline__ void gbar(unsigned* flags, unsigned* gen,
                                     unsigned& g, int bid) {
  const unsigned tgt = g + 1u;
  asm volatile("s_waitcnt vmcnt(0)" ::: "memory");  // drain this wave's stores
  __syncthreads();                                  // all waves drained
  if (threadIdx.x == 0) st32u(flags + bid * 32, tgt);
  if (bid == 0) {
    const int i = threadIdx.x;
    unsigned* fp = flags + i * 32;
    for (;;) {
      unsigned v = (i < NBLK)
          ? __hip_atomic_load(fp, __ATOMIC_RELAXED, __HIP_MEMORY_SCOPE_AGENT)
          : tgt;
      if (__syncthreads_and((int)(v >= tgt))) break;
      __builtin_amdgcn_s_sleep(1);
    }
    if (threadIdx.x == 0)
      __hip_atomic_store(gen, tgt, __ATOMIC_RELAXED, __HIP_MEMORY_SCOPE_AGENT);
  } else {
    if (threadIdx.x == 0) {
      while (__hip_atomic_load(gen, __ATOMIC_RELAXED, __HIP_MEMORY_SCOPE_AGENT) < tgt)
        __builtin_amdgcn_s_sleep(2);
    }
    __syncthreads();
  }
  (void)__hip_atomic_load(gen, __ATOMIC_ACQUIRE, __HIP_MEMORY_SCOPE_AGENT);
  g = tgt;
}

// ---------------- init: fp32 -> bf16 conversions, bias sums, state init ----
__global__ void init_kernel(Params p) {
  long gid = (long)blockIdx.x * blockDim.x + threadIdx.x;
  long stride = (long)gridDim.x * blockDim.x;
  const long nw0i = 4096L * kD, nwh = 4096L * kH, nfc = (long)kD * kH;
  for (long i = gid; i < nw0i; i += stride) p.wb0i[i] = f2b(p.Wi0[i]);
  for (long i = gid; i < nwh; i += stride) {
    p.wb0h[i] = f2b(p.Wh0[i]);
    p.wb1i[i] = f2b(p.Wi1[i]);
    p.wb1h[i] = f2b(p.Wh1[i]);
    p.wb2i[i] = f2b(p.Wi2[i]);
    p.wb2h[i] = f2b(p.Wh2[i]);
  }
  for (long i = gid; i < nfc; i += stride) p.wbfc[i] = f2b(p.Wfc[i]);
  for (long i = gid; i < 4096; i += stride) {
    p.b0[i] = p.bi0[i] + p.bh0[i];
    p.b1[i] = p.bi1[i] + p.bh1[i];
    p.b2[i] = p.bi2[i] + p.bh2[i];
  }
  for (long i = gid; i < kD; i += stride) p.bfcs[i] = p.bfc[i];
  for (long i = gid; i < NFLAG; i += stride) p.bflags[i] = 0u;  // barrier state
  long nx = (long)p.P * kB * kD;
  for (long i = gid; i < nx; i += stride) {
    p.xb[i] = f2b(p.x[i]);
    p.out[i] = p.x[i];  // teacher-forced rows are exact copies
  }
  long nh = (long)kL * kB * kH;
  for (long i = gid; i < nh; i += stride) p.hA[i] = f2b(p.h0[i]);
}

// ---------------- persistent RNN: weights live in VGPRs, 8-way K-split ----
// 128 blocks x 512 thr. Block owns 8 hidden units [8b,8b+8) x 4 gates = 32
// gate-rows/layer as TWO n-tiles: tile j = gates {2j,2j+1}; col c -> gate
// 2j+(c>>3), unit c&7. Wave w (0..7) owns 1/8 of K; partials sum via LDS.
// MFMA 16x16x32: A row=lane&15(m), k=(lane>>4)*8+j; D col=lane&15, row=kq*4+r.
// Gen-phase FC is computed REDUNDANTLY by every block at the start of the
// L0 phase (from h2 of the previous step, already published) -> 3 barriers
// per step instead of 4, no curx broadcast buffer.
__global__ void __launch_bounds__(NTHR) rnn_kernel(Params p) {
  const int tid = threadIdx.x, bid = blockIdx.x;
  const int lane = tid & 63, w = tid >> 6;  // 8 waves
  const int colc = lane & 15, kq = lane >> 4;
  const int aoff = kq * 8;
  const int u7 = colc & 7, gh = colc >> 3;
  const long wr0 = (long)gh * kH + bid * 8 + u7;        // gate-rows 0/1 tile
  const long wr1 = (long)(2 + gh) * kH + bid * 8 + u7;  // gate-rows 2/3 tile
  unsigned* bgen = p.bflags + NBLK * 32 + 32;
  unsigned bg = 0;

  // ---- one-time weight preload: 42 tiles = 168 VGPRs/wave ----
  const int cnt0 = (w < 4) ? 5 : 4;
  const int off0 = (w < 4) ? w * 5 : 20 + (w - 4) * 4;
  v8s w0[2][5], w1[2][8], w2[2][8];
#pragma unroll
  for (int i = 0; i < 5; ++i)
    if (i < cnt0) {
      int gt = off0 + i;
      if (gt < 4) {
        w0[0][i] = *(const v8s*)(p.wb0i + wr0 * kD + gt * 32 + aoff);
        w0[1][i] = *(const v8s*)(p.wb0i + wr1 * kD + gt * 32 + aoff);
      } else {
        w0[0][i] = *(const v8s*)(p.wb0h + wr0 * kH + (gt - 4) * 32 + aoff);
        w0[1][i] = *(const v8s*)(p.wb0h + wr1 * kH + (gt - 4) * 32 + aoff);
      }
    }
#pragma unroll
  for (int i = 0; i < 8; ++i) {
    int gt = w * 8 + i;
    const u16* s1 = (gt < 32) ? p.wb1i : p.wb1h;
    const u16* s2 = (gt < 32) ? p.wb2i : p.wb2h;
    int k = (gt & 31) * 32 + aoff;
    w1[0][i] = *(const v8s*)(s1 + wr0 * kH + k);
    w1[1][i] = *(const v8s*)(s1 + wr1 * kH + k);
    w2[0][i] = *(const v8s*)(s2 + wr0 * kH + k);
    w2[1][i] = *(const v8s*)(s2 + wr1 * kH + k);
  }

  // ---- per-thread cell state: 1 (batch, unit) cell per layer ----
  const int em = tid >> 3, eu = tid & 7;
  const int ehid = bid * 8 + eu;
  float cst[kL], brg[kL][4];
#pragma unroll
  for (int l = 0; l < kL; ++l)
    cst[l] = p.c0[(long)l * kB * kH + (long)em * kH + ehid];
  {
    const float* bp[3] = {p.b0, p.b1, p.b2};
#pragma unroll
    for (int l = 0; l < 3; ++l)
#pragma unroll
      for (int gg = 0; gg < 4; ++gg) brg[l][gg] = bp[l][gg * kH + ehid];
  }

  __shared__ float lg[8][64][18];  // stride 18: <=2-way bank aliasing
  __shared__ u16 xsh[64 * XS];     // current-step input x(t), bf16
  __shared__ u16 hsh[64][8];       // block's h-slice staging for coalesced store
  const int T = p.T, P = p.P;
  const f32x4 z4 = {0.f, 0.f, 0.f, 0.f};
  const float bfc_r = p.bfcs[w * 16 + colc];          // per-thread FC bias
  const u16* wfc_r = p.wbfc + (long)(w * 16 + colc) * kH + aoff;  // FC B row

  auto epilogue = [&](int l, f32x4(&acc)[2][4], u16* hOut) {
    float pre[4];
#pragma unroll
    for (int mt = 0; mt < 4; ++mt)
#pragma unroll
      for (int r = 0; r < 4; ++r) lg[w][mt * 16 + kq * 4 + r][colc] = acc[0][mt][r];
    __syncthreads();
    {
      float s0 = 0.f, s1 = 0.f;
#pragma unroll
      for (int ww = 0; ww < 8; ++ww) {
        s0 += lg[ww][em][eu];
        s1 += lg[ww][em][8 + eu];
      }
      pre[0] = s0;
      pre[1] = s1;
    }
    __syncthreads();
#pragma unroll
    for (int mt = 0; mt < 4; ++mt)
#pragma unroll
      for (int r = 0; r < 4; ++r) lg[w][mt * 16 + kq * 4 + r][colc] = acc[1][mt][r];
    __syncthreads();
    {
      float s0 = 0.f, s1 = 0.f;
#pragma unroll
      for (int ww = 0; ww < 8; ++ww) {
        s0 += lg[ww][em][eu];
        s1 += lg[ww][em][8 + eu];
      }
      pre[2] = s0;
      pre[3] = s1;
    }
    float iv = pre[0] + brg[l][0], fv = pre[1] + brg[l][1];
    float gv = pre[2] + brg[l][2], ov = pre[3] + brg[l][3];
    float cn = sigm(fv) * cst[l] + sigm(iv) * tanhf(gv);
    cst[l] = cn;
    hsh[em][eu] = f2b(sigm(ov) * tanhf(cn));
    __syncthreads();  // hsh complete
    // 64x16B coalesced write-through publish (vs 512x2B): faster vmcnt drain
    if (tid < 64)
      st128(hOut + (long)tid * kH + bid * 8, *(const v8s*)&hsh[tid][0]);
  };

  for (int t = 0; t < T - 1; ++t) {
    const u16* hOld = (t & 1) ? p.hB : p.hA;
    u16* hNew = (t & 1) ? p.hA : p.hB;

    // ===== stage x(t) into LDS: teacher-forced copy, or redundant FC =====
    if (t < P) {
      const u16* xg = p.xb + (long)t * kB * kD;
      for (int j = tid; j < (kB * kD) / 8; j += NTHR) {
        int bb = j >> 4, k8 = (j & 15) * 8;
        *(v8s*)(xsh + bb * XS + k8) = *(const v8s*)(xg + bb * kD + k8);
      }
    } else {
      // x(t) = sigmoid(h2(t-1) @ Wfc^T + bfc); h2(t-1) = layer-2 slab of hOld,
      // published by barrier 3 of the previous iteration. Wave w owns n-tile w
      // (out dims w*16..w*16+15), m-tiles 0..3, full K=1024. 128 MFMA/wave.
      const u16* ap = hOld + 2L * kB * kH + (long)colc * kH + aoff;
      f32x4 fa[4] = {z4, z4, z4, z4};
#pragma unroll 4
      for (int kk = 0; kk < 32; ++kk) {
        v8s b = *(const v8s*)(wfc_r + kk * 32);
#pragma unroll
        for (int mt = 0; mt < 4; ++mt) {
          v8s a = *(const v8s*)(ap + mt * 16 * kH + kk * 32);
          fa[mt] = __builtin_amdgcn_mfma_f32_16x16x32_bf16(a, b, fa[mt], 0, 0, 0);
        }
      }
      float* orow = p.out + (long)t * (kB * kD);
#pragma unroll
      for (int mt = 0; mt < 4; ++mt)
#pragma unroll
        for (int r = 0; r < 4; ++r) {
          float val = sigm(fa[mt][r] + bfc_r);
          int bb = mt * 16 + kq * 4 + r, d = w * 16 + colc;
          xsh[bb * XS + d] = f2b(val);
          if (bid == 0) st32(orow + (long)bb * kD + d, val);  // emit out[t]
        }
    }
    __syncthreads();  // xsh ready

    // ===== layer 0 (x-part from LDS, h-part from hOld) =====
    {
      f32x4 acc[2][4] = {z4, z4, z4, z4, z4, z4, z4, z4};
#pragma unroll
      for (int i = 0; i < 5; ++i)
        if (i < cnt0) {
          int gt = off0 + i;
          if (gt < 4) {
            int k = gt * 32 + aoff;
#pragma unroll
            for (int mt = 0; mt < 4; ++mt) {
              v8s a = *(const v8s*)(xsh + (mt * 16 + colc) * XS + k);
              acc[0][mt] = __builtin_amdgcn_mfma_f32_16x16x32_bf16(a, w0[0][i], acc[0][mt], 0, 0, 0);
              acc[1][mt] = __builtin_amdgcn_mfma_f32_16x16x32_bf16(a, w0[1][i], acc[1][mt], 0, 0, 0);
            }
          } else {
            int k = (gt - 4) * 32 + aoff;
#pragma unroll
            for (int mt = 0; mt < 4; ++mt) {
              v8s a = *(const v8s*)(hOld + (long)(mt * 16 + colc) * kH + k);
              acc[0][mt] = __builtin_amdgcn_mfma_f32_16x16x32_bf16(a, w0[0][i], acc[0][mt], 0, 0, 0);
              acc[1][mt] = __builtin_amdgcn_mfma_f32_16x16x32_bf16(a, w0[1][i], acc[1][mt], 0, 0, 0);
            }
          }
        }
      epilogue(0, acc, hNew);
    }
    gbar(p.bflags, bgen, bg, bid);

    // ===== layer 1 (x-part = h_l0 new, h-part = h_l1 old) =====
    {
      f32x4 acc[2][4] = {z4, z4, z4, z4, z4, z4, z4, z4};
      const u16* Ax = hNew;
      const u16* Ah = hOld + (long)kB * kH;
#pragma unroll
      for (int i = 0; i < 8; ++i) {
        int gt = w * 8 + i;
        const u16* Ab = (gt < 32) ? Ax : Ah;
        int k = (gt & 31) * 32 + aoff;
#pragma unroll
        for (int mt = 0; mt < 4; ++mt) {
          v8s a = *(const v8s*)(Ab + (long)(mt * 16 + colc) * kH + k);
          acc[0][mt] = __builtin_amdgcn_mfma_f32_16x16x32_bf16(a, w1[0][i], acc[0][mt], 0, 0, 0);
          acc[1][mt] = __builtin_amdgcn_mfma_f32_16x16x32_bf16(a, w1[1][i], acc[1][mt], 0, 0, 0);
        }
      }
      epilogue(1, acc, hNew + (long)kB * kH);
    }
    gbar(p.bflags, bgen, bg, bid);

    // ===== layer 2 =====
    {
      f32x4 acc[2][4] = {z4, z4, z4, z4, z4, z4, z4, z4};
      const u16* Ax = hNew + (long)kB * kH;
      const u16* Ah = hOld + 2L * kB * kH;
#pragma unroll
      for (int i = 0; i < 8; ++i) {
        int gt = w * 8 + i;
        const u16* Ab = (gt < 32) ? Ax : Ah;
        int k = (gt & 31) * 32 + aoff;
#pragma unroll
        for (int mt = 0; mt < 4; ++mt) {
          v8s a = *(const v8s*)(Ab + (long)(mt * 16 + colc) * kH + k);
          acc[0][mt] = __builtin_amdgcn_mfma_f32_16x16x32_bf16(a, w2[0][i], acc[0][mt], 0, 0, 0);
          acc[1][mt] = __builtin_amdgcn_mfma_f32_16x16x32_bf16(a, w2[1][i], acc[1][mt], 0, 0, 0);
        }
      }
      epilogue(2, acc, hNew + 2L * kB * kH);
    }
    gbar(p.bflags, bgen, bg, bid);
  }

  // ===== final emitted row out[T-1]: FC from h2(T-2), block 0 only =====
  if (bid == 0 && T - 1 >= P && T >= 2) {
    const u16* hL = ((T - 2) & 1) ? p.hA : p.hB;  // hNew of iteration T-2
    const u16* ap = hL + 2L * kB * kH + (long)colc * kH + aoff;
    f32x4 fa[4] = {z4, z4, z4, z4};
#pragma unroll 4
    for (int kk = 0; kk < 32; ++kk) {
      v8s b = *(const v8s*)(wfc_r + kk * 32);
#pragma unroll
      for (int mt = 0; mt < 4; ++mt) {
        v8s a = *(const v8s*)(ap + mt * 16 * kH + kk * 32);
        fa[mt] = __builtin_amdgcn_mfma_f32_16x16x32_bf16(a, b, fa[mt], 0, 0, 0);
      }
    }
    float* orow = p.out + (long)(T - 1) * (kB * kD);
#pragma unroll
    for (int mt = 0; mt < 4; ++mt)
#pragma unroll
      for (int r = 0; r < 4; ++r) {
        int bb = mt * 16 + kq * 4 + r, d = w * 16 + colc;
        st32(orow + (long)bb * kD + d, sigm(fa[mt][r] + bfc_r));
      }
  }
}

extern "C" void kernel_launch(void* const* d_in, const int* in_sizes, int n_in,
                              void* d_out, int out_size, void* d_ws, size_t ws_size,
                              hipStream_t stream) {
  Params p;
  p.x   = (const float*)d_in[0];
  p.h0  = (const float*)d_in[1];
  p.c0  = (const float*)d_in[2];
  p.Wi0 = (const float*)d_in[3];
  p.Wh0 = (const float*)d_in[4];
  p.bi0 = (const float*)d_in[5];
  p.bh0 = (const float*)d_in[6];
  p.Wi1 = (const float*)d_in[7];
  p.Wh1 = (const float*)d_in[8];
  p.bi1 = (const float*)d_in[9];
  p.bh1 = (const float*)d_in[10];
  p.Wi2 = (const float*)d_in[11];
  p.Wh2 = (const float*)d_in[12];
  p.bi2 = (const float*)d_in[13];
  p.bh2 = (const float*)d_in[14];
  p.Wfc = (const float*)d_in[15];
  p.bfc = (const float*)d_in[16];
  p.out = (float*)d_out;
  p.P = in_sizes[0] / (kB * kD);
  p.T = out_size / (kB * kD);

  char* w = (char*)d_ws;
  auto alloc = [&](size_t bytes) {
    char* r = w;
    w += (bytes + 255) & ~(size_t)255;
    return r;
  };
  p.wb0i = (u16*)alloc(4096L * kD * 2);
  p.wb0h = (u16*)alloc(4096L * kH * 2);
  p.wb1i = (u16*)alloc(4096L * kH * 2);
  p.wb1h = (u16*)alloc(4096L * kH * 2);
  p.wb2i = (u16*)alloc(4096L * kH * 2);
  p.wb2h = (u16*)alloc(4096L * kH * 2);
  p.wbfc = (u16*)alloc((long)kD * kH * 2);
  p.xb   = (u16*)alloc((long)p.P * kB * kD * 2);
  p.hA   = (u16*)alloc((long)kL * kB * kH * 2);
  p.hB   = (u16*)alloc((long)kL * kB * kH * 2);
  p.b0   = (float*)alloc(4096 * 4);
  p.b1   = (float*)alloc(4096 * 4);
  p.b2   = (float*)alloc(4096 * 4);
  p.bfcs = (float*)alloc(kD * 4);
  p.bflags = (unsigned*)alloc(NFLAG * 4);

  hipLaunchKernelGGL(init_kernel, dim3(512), dim3(256), 0, stream, p);
  void* args[] = { &p };
  hipLaunchCooperativeKernel((const void*)rnn_kernel, dim3(NBLK), dim3(NTHR),
                             args, 0, stream);
}

// Round 3
// 24097.971 us; speedup vs baseline: 1.9380x; 1.9358x over previous
//
#include <hip/hip_runtime.h>

typedef short v8s __attribute__((ext_vector_type(8)));
typedef float f32x4 __attribute__((ext_vector_type(4)));
typedef unsigned short u16;

static constexpr int kB = 64;    // batch
static constexpr int kH = 1024;  // hidden
static constexpr int kD = 128;   // input dim
static constexpr int kL = 3;     // layers
static constexpr int NBLK = 128; // proven cooperative grid size
static constexpr int NTHR = 512; // 8 waves -> 8-way K-split
static constexpr int NFLAG = 8192;  // barrier flag words (128 lines + gen + 32 xflags)

__device__ __forceinline__ u16 f2b(float f) {
  union { float f; unsigned u; } v; v.f = f;
  unsigned r = v.u + 0x7fffu + ((v.u >> 16) & 1u);
  return (u16)(r >> 16);
}

__device__ __forceinline__ float sigm(float x) { return 1.f / (1.f + expf(-x)); }

// Write-through stores: land at LLC (coherent point), leave no dirty L2 lines.
__device__ __forceinline__ void st16(u16* p, u16 v) {
  unsigned d = v;
  asm volatile("global_store_short %0, %1, off sc0 sc1" :: "v"(p), "v"(d) : "memory");
}
__device__ __forceinline__ void st32(float* p, float v) {
  asm volatile("global_store_dword %0, %1, off sc0 sc1" :: "v"(p), "v"(v) : "memory");
}
__device__ __forceinline__ void st32u(unsigned* p, unsigned v) {
  asm volatile("global_store_dword %0, %1, off sc0 sc1" :: "v"(p), "v"(v) : "memory");
}

struct Params {
  const float *x, *h0, *c0;
  const float *Wi0, *Wh0, *bi0, *bh0;
  const float *Wi1, *Wh1, *bi1, *bh1;
  const float *Wi2, *Wh2, *bi2, *bh2;
  const float *Wfc, *bfc;
  float *out;
  u16 *wb0i, *wb0h, *wb1i, *wb1h, *wb2i, *wb2h, *wbfc;
  u16 *xb, *hA, *hB, *curx;
  float *b0, *b1, *b2, *bfcs;
  unsigned *bflags;  // flags[b*32]; gen at [NBLK*32+32]; xflags at [(NBLK+2)*32 + i*32]
  int P, T;
};

// PROVEN two-hop grid barrier (round-0 core, 18.3us/phase) with ONE change:
// the exit acquire-inv (buffer_inv: L1 of this CU + L2 of this XCD) runs on
// thread 0 only, then __syncthreads orders all other waves after it. The
// round-0 version ran it per-thread -> 8 redundant L2-invalidate ops/block.
__device__ __forceinline__ void gbar(unsigned* flags, unsigned* gen,
                                     unsigned& g, int bid) {
  const unsigned tgt = g + 1u;
  asm volatile("s_waitcnt vmcnt(0)" ::: "memory");  // drain this wave's stores
  __syncthreads();                                  // all waves drained
  if (threadIdx.x == 0) st32u(flags + bid * 32, tgt);
  if (bid == 0) {
    const int i = threadIdx.x;
    unsigned* fp = flags + i * 32;
    for (;;) {
      unsigned v = (i < NBLK)
          ? __hip_atomic_load(fp, __ATOMIC_RELAXED, __HIP_MEMORY_SCOPE_AGENT)
          : tgt;
      if (__syncthreads_and((int)(v >= tgt))) break;
      __builtin_amdgcn_s_sleep(1);
    }
    if (threadIdx.x == 0)
      __hip_atomic_store(gen, tgt, __ATOMIC_RELAXED, __HIP_MEMORY_SCOPE_AGENT);
  } else {
    if (threadIdx.x == 0) {
      while (__hip_atomic_load(gen, __ATOMIC_RELAXED, __HIP_MEMORY_SCOPE_AGENT) < tgt)
        __builtin_amdgcn_s_sleep(2);
    }
  }
  if (threadIdx.x == 0)
    (void)__hip_atomic_load(gen, __ATOMIC_ACQUIRE, __HIP_MEMORY_SCOPE_AGENT);
  __syncthreads();  // all waves ordered after the single inv
  g = tgt;
}

// ---------------- init: fp32 -> bf16 conversions, bias sums, state init ----
__global__ void init_kernel(Params p) {
  long gid = (long)blockIdx.x * blockDim.x + threadIdx.x;
  long stride = (long)gridDim.x * blockDim.x;
  const long nw0i = 4096L * kD, nwh = 4096L * kH, nfc = (long)kD * kH;
  for (long i = gid; i < nw0i; i += stride) p.wb0i[i] = f2b(p.Wi0[i]);
  for (long i = gid; i < nwh; i += stride) {
    p.wb0h[i] = f2b(p.Wh0[i]);
    p.wb1i[i] = f2b(p.Wi1[i]);
    p.wb1h[i] = f2b(p.Wh1[i]);
    p.wb2i[i] = f2b(p.Wi2[i]);
    p.wb2h[i] = f2b(p.Wh2[i]);
  }
  for (long i = gid; i < nfc; i += stride) p.wbfc[i] = f2b(p.Wfc[i]);
  for (long i = gid; i < 4096; i += stride) {
    p.b0[i] = p.bi0[i] + p.bh0[i];
    p.b1[i] = p.bi1[i] + p.bh1[i];
    p.b2[i] = p.bi2[i] + p.bh2[i];
  }
  for (long i = gid; i < kD; i += stride) p.bfcs[i] = p.bfc[i];
  for (long i = gid; i < NFLAG; i += stride) p.bflags[i] = 0u;  // barrier state
  long nx = (long)p.P * kB * kD;
  for (long i = gid; i < nx; i += stride) {
    p.xb[i] = f2b(p.x[i]);
    p.out[i] = p.x[i];  // teacher-forced rows are exact copies
  }
  long nh = (long)kL * kB * kH;
  for (long i = gid; i < nh; i += stride) p.hA[i] = f2b(p.h0[i]);
}

// ---------------- persistent RNN: weights live in VGPRs, 8-way K-split ----
// 128 blocks x 512 thr. Block owns 8 hidden units [8b,8b+8) x 4 gates = 32
// gate-rows/layer as TWO n-tiles: tile j = gates {2j,2j+1}; col c -> gate
// 2j+(c>>3), unit c&7. Wave w (0..7) owns 1/8 of K; partials sum via LDS.
// MFMA 16x16x32: A row=lane&15(m), k=(lane>>4)*8+j; D col=lane&15, row=kq*4+r.
// Gen-phase FC: producer-consumer INSIDE the L0 phase (no 4th barrier, no
// redundancy). Blocks 0-7 / waves 0-3 compute distinct FC tiles of x(t) from
// h2(t-1), publish curx + per-wave flag; the only consumer of x (wave 0 of
// each block) does its h-tile, spins on the 32 flags, acquire-invs, then
// runs its 4 x-tile MFMAs. 3 barriers/step uniformly.
__global__ void __launch_bounds__(NTHR) rnn_kernel(Params p) {
  const int tid = threadIdx.x, bid = blockIdx.x;
  const int lane = tid & 63, w = tid >> 6;  // 8 waves
  const int colc = lane & 15, kq = lane >> 4;
  const int aoff = kq * 8;
  const int u7 = colc & 7, gh = colc >> 3;
  const long wr0 = (long)gh * kH + bid * 8 + u7;        // gate-rows 0/1 tile
  const long wr1 = (long)(2 + gh) * kH + bid * 8 + u7;  // gate-rows 2/3 tile
  unsigned* bgen = p.bflags + NBLK * 32 + 32;
  unsigned* xflag = p.bflags + (NBLK + 2) * 32;  // 32 lines, one per FC wave
  unsigned bg = 0;

  // ---- one-time weight preload: 42 tiles = 168 VGPRs/wave ----
  const int cnt0 = (w < 4) ? 5 : 4;
  const int off0 = (w < 4) ? w * 5 : 20 + (w - 4) * 4;
  v8s w0[2][5], w1[2][8], w2[2][8];
#pragma unroll
  for (int i = 0; i < 5; ++i)
    if (i < cnt0) {
      int gt = off0 + i;
      if (gt < 4) {
        w0[0][i] = *(const v8s*)(p.wb0i + wr0 * kD + gt * 32 + aoff);
        w0[1][i] = *(const v8s*)(p.wb0i + wr1 * kD + gt * 32 + aoff);
      } else {
        w0[0][i] = *(const v8s*)(p.wb0h + wr0 * kH + (gt - 4) * 32 + aoff);
        w0[1][i] = *(const v8s*)(p.wb0h + wr1 * kH + (gt - 4) * 32 + aoff);
      }
    }
#pragma unroll
  for (int i = 0; i < 8; ++i) {
    int gt = w * 8 + i;
    const u16* s1 = (gt < 32) ? p.wb1i : p.wb1h;
    const u16* s2 = (gt < 32) ? p.wb2i : p.wb2h;
    int k = (gt & 31) * 32 + aoff;
    w1[0][i] = *(const v8s*)(s1 + wr0 * kH + k);
    w1[1][i] = *(const v8s*)(s1 + wr1 * kH + k);
    w2[0][i] = *(const v8s*)(s2 + wr0 * kH + k);
    w2[1][i] = *(const v8s*)(s2 + wr1 * kH + k);
  }

  // ---- per-thread cell state: 1 (batch, unit) cell per layer ----
  const int em = tid >> 3, eu = tid & 7;
  const int ehid = bid * 8 + eu;
  float cst[kL], brg[kL][4];
#pragma unroll
  for (int l = 0; l < kL; ++l)
    cst[l] = p.c0[(long)l * kB * kH + (long)em * kH + ehid];
  {
    const float* bp[3] = {p.b0, p.b1, p.b2};
#pragma unroll
    for (int l = 0; l < 3; ++l)
#pragma unroll
      for (int gg = 0; gg < 4; ++gg) brg[l][gg] = bp[l][gg * kH + ehid];
  }

  __shared__ float lg[8][64][18];  // stride 18: <=2-way bank aliasing
  const int T = p.T, P = p.P;
  const f32x4 z4 = {0.f, 0.f, 0.f, 0.f};

  auto epilogue = [&](int l, f32x4(&acc)[2][4], u16* hOut) {
    float pre[4];
#pragma unroll
    for (int mt = 0; mt < 4; ++mt)
#pragma unroll
      for (int r = 0; r < 4; ++r) lg[w][mt * 16 + kq * 4 + r][colc] = acc[0][mt][r];
    __syncthreads();
    {
      float s0 = 0.f, s1 = 0.f;
#pragma unroll
      for (int ww = 0; ww < 8; ++ww) {
        s0 += lg[ww][em][eu];
        s1 += lg[ww][em][8 + eu];
      }
      pre[0] = s0;
      pre[1] = s1;
    }
    __syncthreads();
#pragma unroll
    for (int mt = 0; mt < 4; ++mt)
#pragma unroll
      for (int r = 0; r < 4; ++r) lg[w][mt * 16 + kq * 4 + r][colc] = acc[1][mt][r];
    __syncthreads();
    {
      float s0 = 0.f, s1 = 0.f;
#pragma unroll
      for (int ww = 0; ww < 8; ++ww) {
        s0 += lg[ww][em][eu];
        s1 += lg[ww][em][8 + eu];
      }
      pre[2] = s0;
      pre[3] = s1;
    }
    float iv = pre[0] + brg[l][0], fv = pre[1] + brg[l][1];
    float gv = pre[2] + brg[l][2], ov = pre[3] + brg[l][3];
    float cn = sigm(fv) * cst[l] + sigm(iv) * tanhf(gv);
    cst[l] = cn;
    st16(hOut + (long)em * kH + ehid, f2b(sigm(ov) * tanhf(cn)));
  };

  for (int t = 0; t < T - 1; ++t) {
    const u16* hOld = (t & 1) ? p.hB : p.hA;
    u16* hNew = (t & 1) ? p.hA : p.hB;
    const bool genstep = (t >= P);

    // ===== FC producer (gen steps): blocks 0-7, waves 0-3, distinct tiles.
    // x(t) = sigmoid(h2(t-1) @ Wfc^T + bfc). h2(t-1) is visible: published
    // before barrier 3 of step t-1. Publish curx tile, drain, set wave flag.
    if (genstep && bid < 8 && w < 4) {
      f32x4 u0 = z4, u1 = z4;
      const u16* ap = hOld + 2L * kB * kH + (long)(w * 16 + colc) * kH + aoff;
      const u16* bp = p.wbfc + (long)(bid * 16 + colc) * kH + aoff;
#pragma unroll
      for (int i = 0; i < 16; ++i) {
        v8s a0 = *(const v8s*)(ap + i * 32);
        v8s b0 = *(const v8s*)(bp + i * 32);
        v8s a1 = *(const v8s*)(ap + 512 + i * 32);
        v8s b1 = *(const v8s*)(bp + 512 + i * 32);
        u0 = __builtin_amdgcn_mfma_f32_16x16x32_bf16(a0, b0, u0, 0, 0, 0);
        u1 = __builtin_amdgcn_mfma_f32_16x16x32_bf16(a1, b1, u1, 0, 0, 0);
      }
      float bv = p.bfcs[bid * 16 + colc];
#pragma unroll
      for (int r = 0; r < 4; ++r) {
        float val = sigm(u0[r] + u1[r] + bv);
        int bb = w * 16 + kq * 4 + r, d = bid * 16 + colc;
        st32(p.out + (long)t * (kB * kD) + (long)bb * kD + d, val);
        st16(p.curx + (long)bb * kD + d, f2b(val));
      }
      asm volatile("s_waitcnt vmcnt(0)" ::: "memory");  // curx tile visible
      if (lane == 0)
        st32u(xflag + (bid * 4 + w) * 32, (unsigned)(t - P + 1));
    }

    // ===== layer 0 =====
    {
      f32x4 acc[2][4] = {z4, z4, z4, z4, z4, z4, z4, z4};
      // h-part first (all waves; wave 0's gt=4 tile included)
#pragma unroll
      for (int i = 0; i < 5; ++i)
        if (i < cnt0) {
          int gt = off0 + i;
          if (gt >= 4) {
            int k = (gt - 4) * 32 + aoff;
#pragma unroll
            for (int mt = 0; mt < 4; ++mt) {
              v8s a = *(const v8s*)(hOld + (long)(mt * 16 + colc) * kH + k);
              acc[0][mt] = __builtin_amdgcn_mfma_f32_16x16x32_bf16(a, w0[0][i], acc[0][mt], 0, 0, 0);
              acc[1][mt] = __builtin_amdgcn_mfma_f32_16x16x32_bf16(a, w0[1][i], acc[1][mt], 0, 0, 0);
            }
          }
        }
      // x-part: wave 0 only (gt 0..3). Gen steps: wait for the 32 FC flags.
      if (w == 0) {
        const u16* xin;
        if (genstep) {
          const unsigned tag = (unsigned)(t - P + 1);
          unsigned* xf = xflag + (lane & 31) * 32;
          for (;;) {
            unsigned v = (lane < 32)
                ? __hip_atomic_load(xf, __ATOMIC_RELAXED, __HIP_MEMORY_SCOPE_AGENT)
                : tag;
            if (__all((int)(v >= tag))) break;
            __builtin_amdgcn_s_sleep(1);
          }
          // one acquire (buffer_inv) wave-wide: kill stale L1/L2 before curx
          (void)__hip_atomic_load(xflag, __ATOMIC_ACQUIRE, __HIP_MEMORY_SCOPE_AGENT);
          xin = p.curx;
        } else {
          xin = p.xb + (long)t * kB * kD;
        }
#pragma unroll
        for (int gt = 0; gt < 4; ++gt) {
          int k = gt * 32 + aoff;
#pragma unroll
          for (int mt = 0; mt < 4; ++mt) {
            v8s a = *(const v8s*)(xin + (long)(mt * 16 + colc) * kD + k);
            acc[0][mt] = __builtin_amdgcn_mfma_f32_16x16x32_bf16(a, w0[0][gt], acc[0][mt], 0, 0, 0);
            acc[1][mt] = __builtin_amdgcn_mfma_f32_16x16x32_bf16(a, w0[1][gt], acc[1][mt], 0, 0, 0);
          }
        }
      }
      epilogue(0, acc, hNew);
    }
    gbar(p.bflags, bgen, bg, bid);

    // ===== layer 1 (x-part = h_l0 new, h-part = h_l1 old) =====
    {
      f32x4 acc[2][4] = {z4, z4, z4, z4, z4, z4, z4, z4};
      const u16* Ax = hNew;
      const u16* Ah = hOld + (long)kB * kH;
#pragma unroll
      for (int i = 0; i < 8; ++i) {
        int gt = w * 8 + i;
        const u16* Ab = (gt < 32) ? Ax : Ah;
        int k = (gt & 31) * 32 + aoff;
#pragma unroll
        for (int mt = 0; mt < 4; ++mt) {
          v8s a = *(const v8s*)(Ab + (long)(mt * 16 + colc) * kH + k);
          acc[0][mt] = __builtin_amdgcn_mfma_f32_16x16x32_bf16(a, w1[0][i], acc[0][mt], 0, 0, 0);
          acc[1][mt] = __builtin_amdgcn_mfma_f32_16x16x32_bf16(a, w1[1][i], acc[1][mt], 0, 0, 0);
        }
      }
      epilogue(1, acc, hNew + (long)kB * kH);
    }
    gbar(p.bflags, bgen, bg, bid);

    // ===== layer 2 =====
    {
      f32x4 acc[2][4] = {z4, z4, z4, z4, z4, z4, z4, z4};
      const u16* Ax = hNew + (long)kB * kH;
      const u16* Ah = hOld + 2L * kB * kH;
#pragma unroll
      for (int i = 0; i < 8; ++i) {
        int gt = w * 8 + i;
        const u16* Ab = (gt < 32) ? Ax : Ah;
        int k = (gt & 31) * 32 + aoff;
#pragma unroll
        for (int mt = 0; mt < 4; ++mt) {
          v8s a = *(const v8s*)(Ab + (long)(mt * 16 + colc) * kH + k);
          acc[0][mt] = __builtin_amdgcn_mfma_f32_16x16x32_bf16(a, w2[0][i], acc[0][mt], 0, 0, 0);
          acc[1][mt] = __builtin_amdgcn_mfma_f32_16x16x32_bf16(a, w2[1][i], acc[1][mt], 0, 0, 0);
        }
      }
      epilogue(2, acc, hNew + 2L * kB * kH);
    }
    gbar(p.bflags, bgen, bg, bid);
  }

  // ===== final emitted row out[T-1]: FC from h2(T-2), block 0 only =====
  if (bid == 0 && T - 1 >= P && T >= 2) {
    const u16* hL = ((T - 2) & 1) ? p.hA : p.hB;  // hNew of iteration T-2
    const u16* wfc_r = p.wbfc + (long)(w * 16 + colc) * kH + aoff;
    const u16* ap = hL + 2L * kB * kH + (long)colc * kH + aoff;
    f32x4 fa[4] = {z4, z4, z4, z4};
#pragma unroll 2
    for (int kk = 0; kk < 32; ++kk) {
      v8s b = *(const v8s*)(wfc_r + kk * 32);
#pragma unroll
      for (int mt = 0; mt < 4; ++mt) {
        v8s a = *(const v8s*)(ap + mt * 16 * kH + kk * 32);
        fa[mt] = __builtin_amdgcn_mfma_f32_16x16x32_bf16(a, b, fa[mt], 0, 0, 0);
      }
    }
    float bv = p.bfcs[w * 16 + colc];
    float* orow = p.out + (long)(T - 1) * (kB * kD);
#pragma unroll
    for (int mt = 0; mt < 4; ++mt)
#pragma unroll
      for (int r = 0; r < 4; ++r) {
        int bb = mt * 16 + kq * 4 + r, d = w * 16 + colc;
        st32(orow + (long)bb * kD + d, sigm(fa[mt][r] + bv));
      }
  }
}

extern "C" void kernel_launch(void* const* d_in, const int* in_sizes, int n_in,
                              void* d_out, int out_size, void* d_ws, size_t ws_size,
                              hipStream_t stream) {
  Params p;
  p.x   = (const float*)d_in[0];
  p.h0  = (const float*)d_in[1];
  p.c0  = (const float*)d_in[2];
  p.Wi0 = (const float*)d_in[3];
  p.Wh0 = (const float*)d_in[4];
  p.bi0 = (const float*)d_in[5];
  p.bh0 = (const float*)d_in[6];
  p.Wi1 = (const float*)d_in[7];
  p.Wh1 = (const float*)d_in[8];
  p.bi1 = (const float*)d_in[9];
  p.bh1 = (const float*)d_in[10];
  p.Wi2 = (const float*)d_in[11];
  p.Wh2 = (const float*)d_in[12];
  p.bi2 = (const float*)d_in[13];
  p.bh2 = (const float*)d_in[14];
  p.Wfc = (const float*)d_in[15];
  p.bfc = (const float*)d_in[16];
  p.out = (float*)d_out;
  p.P = in_sizes[0] / (kB * kD);
  p.T = out_size / (kB * kD);

  char* w = (char*)d_ws;
  auto alloc = [&](size_t bytes) {
    char* r = w;
    w += (bytes + 255) & ~(size_t)255;
    return r;
  };
  p.wb0i = (u16*)alloc(4096L * kD * 2);
  p.wb0h = (u16*)alloc(4096L * kH * 2);
  p.wb1i = (u16*)alloc(4096L * kH * 2);
  p.wb1h = (u16*)alloc(4096L * kH * 2);
  p.wb2i = (u16*)alloc(4096L * kH * 2);
  p.wb2h = (u16*)alloc(4096L * kH * 2);
  p.wbfc = (u16*)alloc((long)kD * kH * 2);
  p.xb   = (u16*)alloc((long)p.P * kB * kD * 2);
  p.hA   = (u16*)alloc((long)kL * kB * kH * 2);
  p.hB   = (u16*)alloc((long)kL * kB * kH * 2);
  p.curx = (u16*)alloc((long)kB * kD * 2);
  p.b0   = (float*)alloc(4096 * 4);
  p.b1   = (float*)alloc(4096 * 4);
  p.b2   = (float*)alloc(4096 * 4);
  p.bfcs = (float*)alloc(kD * 4);
  p.bflags = (unsigned*)alloc(NFLAG * 4);

  hipLaunchKernelGGL(init_kernel, dim3(512), dim3(256), 0, stream, p);
  void* args[] = { &p };
  hipLaunchCooperativeKernel((const void*)rnn_kernel, dim3(NBLK), dim3(NTHR),
                             args, 0, stream);
}

// Round 4
// 23796.947 us; speedup vs baseline: 1.9625x; 1.0126x over previous
//
#include <hip/hip_runtime.h>

typedef short v8s __attribute__((ext_vector_type(8)));
typedef float f32x4 __attribute__((ext_vector_type(4)));
typedef unsigned short u16;

static constexpr int kB = 64;    // batch
static constexpr int kH = 1024;  // hidden
static constexpr int kD = 128;   // input dim
static constexpr int kL = 3;     // layers
static constexpr int NBLK = 128; // proven cooperative grid size
static constexpr int NTHR = 512; // 8 waves
static constexpr int NFLAG = 8192;  // barrier flag words (128 lines + gen + 32 xflags)

__device__ __forceinline__ u16 f2b(float f) {
  union { float f; unsigned u; } v; v.f = f;
  unsigned r = v.u + 0x7fffu + ((v.u >> 16) & 1u);
  return (u16)(r >> 16);
}

__device__ __forceinline__ float sigm(float x) { return 1.f / (1.f + expf(-x)); }

// Write-through stores: land at LLC (coherent point), leave no dirty L2 lines.
__device__ __forceinline__ void st16(u16* p, u16 v) {
  unsigned d = v;
  asm volatile("global_store_short %0, %1, off sc0 sc1" :: "v"(p), "v"(d) : "memory");
}
__device__ __forceinline__ void st32(float* p, float v) {
  asm volatile("global_store_dword %0, %1, off sc0 sc1" :: "v"(p), "v"(v) : "memory");
}
__device__ __forceinline__ void st32u(unsigned* p, unsigned v) {
  asm volatile("global_store_dword %0, %1, off sc0 sc1" :: "v"(p), "v"(v) : "memory");
}

struct Params {
  const float *x, *h0, *c0;
  const float *Wi0, *Wh0, *bi0, *bh0;
  const float *Wi1, *Wh1, *bi1, *bh1;
  const float *Wi2, *Wh2, *bi2, *bh2;
  const float *Wfc, *bfc;
  float *out;
  u16 *wb0i, *wb0h, *wb1i, *wb1h, *wb2i, *wb2h, *wbfc;
  u16 *xb, *hA, *hB, *curx;
  float *b0, *b1, *b2, *bfcs;
  unsigned *bflags;  // flags[b*32]; gen at [NBLK*32+32]; xflags at [(NBLK+2)*32 + i*32]
  int P, T;
};

// ---------------- init: fp32 -> bf16 conversions, bias sums, state init ----
__global__ void init_kernel(Params p) {
  long gid = (long)blockIdx.x * blockDim.x + threadIdx.x;
  long stride = (long)gridDim.x * blockDim.x;
  const long nw0i = 4096L * kD, nwh = 4096L * kH, nfc = (long)kD * kH;
  for (long i = gid; i < nw0i; i += stride) p.wb0i[i] = f2b(p.Wi0[i]);
  for (long i = gid; i < nwh; i += stride) {
    p.wb0h[i] = f2b(p.Wh0[i]);
    p.wb1i[i] = f2b(p.Wi1[i]);
    p.wb1h[i] = f2b(p.Wh1[i]);
    p.wb2i[i] = f2b(p.Wi2[i]);
    p.wb2h[i] = f2b(p.Wh2[i]);
  }
  for (long i = gid; i < nfc; i += stride) p.wbfc[i] = f2b(p.Wfc[i]);
  for (long i = gid; i < 4096; i += stride) {
    p.b0[i] = p.bi0[i] + p.bh0[i];
    p.b1[i] = p.bi1[i] + p.bh1[i];
    p.b2[i] = p.bi2[i] + p.bh2[i];
  }
  for (long i = gid; i < kD; i += stride) p.bfcs[i] = p.bfc[i];
  for (long i = gid; i < NFLAG; i += stride) p.bflags[i] = 0u;  // barrier state
  long nx = (long)p.P * kB * kD;
  for (long i = gid; i < nx; i += stride) {
    p.xb[i] = f2b(p.x[i]);
    p.out[i] = p.x[i];  // teacher-forced rows are exact copies
  }
  long nh = (long)kL * kB * kH;
  for (long i = gid; i < nh; i += stride) p.hA[i] = f2b(p.h0[i]);
}

// ---------------- persistent RNN: weights in VGPRs, stride-8 K retile ----
// 128 blocks x 512 thr. Block owns 8 hidden units x 4 gates as TWO n-tiles.
// NEW round-4 tiling: wave w owns x k-tiles {w+8i} (i<4) and h k-tiles
// {w+8i} (i<4) of the h-half -> every wave computes its h-part (data 3
// boundaries old, never needs a wait) BEFORE waiting for the previous
// boundary, then its x-part (fresh data) after. Barrier is dissolved into:
//   arrival (drain + per-block flag) at phase end,
//   aggregation+gen-publish by block0/wave0 at top of next phase (overlapped
//     with everyone's h-part),
//   block-wide thread0 gen-poll + single acquire-inv between h- and x-part.
// WAR safety: writer of any h-slab observes (transitively through the
// previous phase's gen-wait) a boundary that postdates all readers of the
// value being overwritten; every block issues >=1 acquire-inv per step
// between a slab's write and its 3-phases-later re-read, so no stale lines.
__global__ void __launch_bounds__(NTHR) rnn_kernel(Params p) {
  const int tid = threadIdx.x, bid = blockIdx.x;
  const int lane = tid & 63, w = tid >> 6;  // 8 waves
  const int colc = lane & 15, kq = lane >> 4;
  const int aoff = kq * 8;
  const int u7 = colc & 7, gh = colc >> 3;
  const long wr0 = (long)gh * kH + bid * 8 + u7;        // gate-rows 0/1 tile
  const long wr1 = (long)(2 + gh) * kH + bid * 8 + u7;  // gate-rows 2/3 tile
  unsigned* bgen = p.bflags + NBLK * 32 + 32;
  unsigned* xflag = p.bflags + (NBLK + 2) * 32;  // 32 lines, one per FC wave
  unsigned bg = 0;

  // ---- one-time weight preload: 42 tiles = 168 VGPRs/wave ----
  v8s w0x[2];  // waves 0-3 only: L0 x k-tile w
  v8s w0h[2][4], w1x[2][4], w1h[2][4], w2x[2][4], w2h[2][4];
  if (w < 4) {
    w0x[0] = *(const v8s*)(p.wb0i + wr0 * kD + w * 32 + aoff);
    w0x[1] = *(const v8s*)(p.wb0i + wr1 * kD + w * 32 + aoff);
  }
#pragma unroll
  for (int i = 0; i < 4; ++i) {
    int k = (w + 8 * i) * 32 + aoff;
    w0h[0][i] = *(const v8s*)(p.wb0h + wr0 * kH + k);
    w0h[1][i] = *(const v8s*)(p.wb0h + wr1 * kH + k);
    w1x[0][i] = *(const v8s*)(p.wb1i + wr0 * kH + k);
    w1x[1][i] = *(const v8s*)(p.wb1i + wr1 * kH + k);
    w1h[0][i] = *(const v8s*)(p.wb1h + wr0 * kH + k);
    w1h[1][i] = *(const v8s*)(p.wb1h + wr1 * kH + k);
    w2x[0][i] = *(const v8s*)(p.wb2i + wr0 * kH + k);
    w2x[1][i] = *(const v8s*)(p.wb2i + wr1 * kH + k);
    w2h[0][i] = *(const v8s*)(p.wb2h + wr0 * kH + k);
    w2h[1][i] = *(const v8s*)(p.wb2h + wr1 * kH + k);
  }

  // ---- per-thread cell state: 1 (batch, unit) cell per layer ----
  const int em = tid >> 3, eu = tid & 7;
  const int ehid = bid * 8 + eu;
  float cst[kL], brg[kL][4];
#pragma unroll
  for (int l = 0; l < kL; ++l)
    cst[l] = p.c0[(long)l * kB * kH + (long)em * kH + ehid];
  {
    const float* bp[3] = {p.b0, p.b1, p.b2};
#pragma unroll
    for (int l = 0; l < 3; ++l)
#pragma unroll
      for (int gg = 0; gg < 4; ++gg) brg[l][gg] = bp[l][gg * kH + ehid];
  }

  __shared__ float lg[8][64][18];  // stride 18: <=2-way bank aliasing
  const int T = p.T, P = p.P;
  const f32x4 z4 = {0.f, 0.f, 0.f, 0.f};

  auto epilogue = [&](int l, f32x4(&acc)[2][4], u16* hOut) {
    float pre[4];
#pragma unroll
    for (int mt = 0; mt < 4; ++mt)
#pragma unroll
      for (int r = 0; r < 4; ++r) lg[w][mt * 16 + kq * 4 + r][colc] = acc[0][mt][r];
    __syncthreads();
    {
      float s0 = 0.f, s1 = 0.f;
#pragma unroll
      for (int ww = 0; ww < 8; ++ww) {
        s0 += lg[ww][em][eu];
        s1 += lg[ww][em][8 + eu];
      }
      pre[0] = s0;
      pre[1] = s1;
    }
    __syncthreads();
#pragma unroll
    for (int mt = 0; mt < 4; ++mt)
#pragma unroll
      for (int r = 0; r < 4; ++r) lg[w][mt * 16 + kq * 4 + r][colc] = acc[1][mt][r];
    __syncthreads();
    {
      float s0 = 0.f, s1 = 0.f;
#pragma unroll
      for (int ww = 0; ww < 8; ++ww) {
        s0 += lg[ww][em][eu];
        s1 += lg[ww][em][8 + eu];
      }
      pre[2] = s0;
      pre[3] = s1;
    }
    float iv = pre[0] + brg[l][0], fv = pre[1] + brg[l][1];
    float gv = pre[2] + brg[l][2], ov = pre[3] + brg[l][3];
    float cn = sigm(fv) * cst[l] + sigm(iv) * tanhf(gv);
    cst[l] = cn;
    st16(hOut + (long)em * kH + ehid, f2b(sigm(ov) * tanhf(cn)));
  };

  // Arrival: per-wave drain -> block sync -> thread0 publishes block flag.
  auto arrive = [&]() {
    bg += 1u;
    asm volatile("s_waitcnt vmcnt(0)" ::: "memory");
    __syncthreads();
    if (tid == 0) st32u(p.bflags + bid * 32, bg);
  };

  // block0/wave0: observe all 128 block flags at boundary bg, publish gen.
  auto aggregate_publish = [&]() {
    unsigned* f0 = p.bflags + lane * 32;
    unsigned* f1 = p.bflags + (64 + lane) * 32;
    for (;;) {
      unsigned a = __hip_atomic_load(f0, __ATOMIC_RELAXED, __HIP_MEMORY_SCOPE_AGENT);
      unsigned b = __hip_atomic_load(f1, __ATOMIC_RELAXED, __HIP_MEMORY_SCOPE_AGENT);
      if (__all((int)(a >= bg && b >= bg))) break;
      __builtin_amdgcn_s_sleep(1);
    }
    if (lane == 0) st32u(bgen, bg);
  };

  // Block-wide wait for gen >= bg (thread0 polls; single acquire-inv).
  auto block_wait_gen = [&]() {
    if (tid == 0) {
      while (__hip_atomic_load(bgen, __ATOMIC_RELAXED, __HIP_MEMORY_SCOPE_AGENT) < bg)
        __builtin_amdgcn_s_sleep(2);
    }
    __syncthreads();
    if (tid == 0)
      (void)__hip_atomic_load(bgen, __ATOMIC_ACQUIRE, __HIP_MEMORY_SCOPE_AGENT);
    __syncthreads();
  };

  for (int t = 0; t < T - 1; ++t) {
    const u16* hOld = (t & 1) ? p.hB : p.hA;
    u16* hNew = (t & 1) ? p.hA : p.hB;
    const bool genstep = (t >= P);

    // ================= phase A: (FC) + L0 =================
    {
      f32x4 acc[2][4] = {z4, z4, z4, z4, z4, z4, z4, z4};
      // h-part: 4 tiles/wave, data 3 boundaries old -> no wait.
#pragma unroll
      for (int i = 0; i < 4; ++i) {
        int k = (w + 8 * i) * 32 + aoff;
#pragma unroll
        for (int mt = 0; mt < 4; ++mt) {
          v8s a = *(const v8s*)(hOld + (long)(mt * 16 + colc) * kH + k);
          acc[0][mt] = __builtin_amdgcn_mfma_f32_16x16x32_bf16(a, w0h[0][i], acc[0][mt], 0, 0, 0);
          acc[1][mt] = __builtin_amdgcn_mfma_f32_16x16x32_bf16(a, w0h[1][i], acc[1][mt], 0, 0, 0);
        }
      }
      // aggregation duty: publish boundary b3(t-1), overlapped with h-parts.
      if (bid == 0 && w == 0) aggregate_publish();
      // FC producer (gen steps): blocks 0-7, waves 0-3, distinct tiles.
      if (genstep && bid < 8 && w < 4) {
        while (__hip_atomic_load(bgen, __ATOMIC_RELAXED, __HIP_MEMORY_SCOPE_AGENT) < bg)
          __builtin_amdgcn_s_sleep(2);
        (void)__hip_atomic_load(bgen, __ATOMIC_ACQUIRE, __HIP_MEMORY_SCOPE_AGENT);
        f32x4 u0 = z4, u1 = z4;
        const u16* ap = hOld + 2L * kB * kH + (long)(w * 16 + colc) * kH + aoff;
        const u16* bp = p.wbfc + (long)(bid * 16 + colc) * kH + aoff;
#pragma unroll
        for (int i = 0; i < 16; ++i) {
          v8s a0 = *(const v8s*)(ap + i * 32);
          v8s b0 = *(const v8s*)(bp + i * 32);
          v8s a1 = *(const v8s*)(ap + 512 + i * 32);
          v8s b1 = *(const v8s*)(bp + 512 + i * 32);
          u0 = __builtin_amdgcn_mfma_f32_16x16x32_bf16(a0, b0, u0, 0, 0, 0);
          u1 = __builtin_amdgcn_mfma_f32_16x16x32_bf16(a1, b1, u1, 0, 0, 0);
        }
        float bv = p.bfcs[bid * 16 + colc];
#pragma unroll
        for (int r = 0; r < 4; ++r) {
          float val = sigm(u0[r] + u1[r] + bv);
          int bb = w * 16 + kq * 4 + r, d = bid * 16 + colc;
          st32(p.out + (long)t * (kB * kD) + (long)bb * kD + d, val);
          st16(p.curx + (long)bb * kD + d, f2b(val));
        }
        asm volatile("s_waitcnt vmcnt(0)" ::: "memory");  // curx tile visible
        if (lane == 0)
          st32u(xflag + (bid * 4 + w) * 32, (unsigned)(t - P + 1));
      }
      // x-part: waves 0-3, one k-tile each.
      if (w < 4) {
        const u16* xin;
        if (genstep) {
          const unsigned tag = (unsigned)(t - P + 1);
          unsigned* xf = xflag + (lane & 31) * 32;
          for (;;) {
            unsigned v = (lane < 32)
                ? __hip_atomic_load(xf, __ATOMIC_RELAXED, __HIP_MEMORY_SCOPE_AGENT)
                : tag;
            if (__all((int)(v >= tag))) break;
            __builtin_amdgcn_s_sleep(1);
          }
          (void)__hip_atomic_load(xflag, __ATOMIC_ACQUIRE, __HIP_MEMORY_SCOPE_AGENT);
          xin = p.curx;
        } else {
          xin = p.xb + (long)t * kB * kD;
        }
        int k = w * 32 + aoff;
#pragma unroll
        for (int mt = 0; mt < 4; ++mt) {
          v8s a = *(const v8s*)(xin + (long)(mt * 16 + colc) * kD + k);
          acc[0][mt] = __builtin_amdgcn_mfma_f32_16x16x32_bf16(a, w0x[0], acc[0][mt], 0, 0, 0);
          acc[1][mt] = __builtin_amdgcn_mfma_f32_16x16x32_bf16(a, w0x[1], acc[1][mt], 0, 0, 0);
        }
      }
      epilogue(0, acc, hNew);
      arrive();
    }

    // ================= phase B: L1 =================
    {
      f32x4 acc[2][4] = {z4, z4, z4, z4, z4, z4, z4, z4};
      const u16* Ax = hNew;                      // h0(t): fresh, needs wait
      const u16* Ah = hOld + (long)kB * kH;      // h1(t-1): 3 boundaries old
#pragma unroll
      for (int i = 0; i < 4; ++i) {
        int k = (w + 8 * i) * 32 + aoff;
#pragma unroll
        for (int mt = 0; mt < 4; ++mt) {
          v8s a = *(const v8s*)(Ah + (long)(mt * 16 + colc) * kH + k);
          acc[0][mt] = __builtin_amdgcn_mfma_f32_16x16x32_bf16(a, w1h[0][i], acc[0][mt], 0, 0, 0);
          acc[1][mt] = __builtin_amdgcn_mfma_f32_16x16x32_bf16(a, w1h[1][i], acc[1][mt], 0, 0, 0);
        }
      }
      if (bid == 0 && w == 0) aggregate_publish();
      block_wait_gen();
#pragma unroll
      for (int i = 0; i < 4; ++i) {
        int k = (w + 8 * i) * 32 + aoff;
#pragma unroll
        for (int mt = 0; mt < 4; ++mt) {
          v8s a = *(const v8s*)(Ax + (long)(mt * 16 + colc) * kH + k);
          acc[0][mt] = __builtin_amdgcn_mfma_f32_16x16x32_bf16(a, w1x[0][i], acc[0][mt], 0, 0, 0);
          acc[1][mt] = __builtin_amdgcn_mfma_f32_16x16x32_bf16(a, w1x[1][i], acc[1][mt], 0, 0, 0);
        }
      }
      epilogue(1, acc, hNew + (long)kB * kH);
      arrive();
    }

    // ================= phase C: L2 =================
    {
      f32x4 acc[2][4] = {z4, z4, z4, z4, z4, z4, z4, z4};
      const u16* Ax = hNew + (long)kB * kH;      // h1(t): fresh, needs wait
      const u16* Ah = hOld + 2L * kB * kH;       // h2(t-1): 3 boundaries old
#pragma unroll
      for (int i = 0; i < 4; ++i) {
        int k = (w + 8 * i) * 32 + aoff;
#pragma unroll
        for (int mt = 0; mt < 4; ++mt) {
          v8s a = *(const v8s*)(Ah + (long)(mt * 16 + colc) * kH + k);
          acc[0][mt] = __builtin_amdgcn_mfma_f32_16x16x32_bf16(a, w2h[0][i], acc[0][mt], 0, 0, 0);
          acc[1][mt] = __builtin_amdgcn_mfma_f32_16x16x32_bf16(a, w2h[1][i], acc[1][mt], 0, 0, 0);
        }
      }
      if (bid == 0 && w == 0) aggregate_publish();
      block_wait_gen();
#pragma unroll
      for (int i = 0; i < 4; ++i) {
        int k = (w + 8 * i) * 32 + aoff;
#pragma unroll
        for (int mt = 0; mt < 4; ++mt) {
          v8s a = *(const v8s*)(Ax + (long)(mt * 16 + colc) * kH + k);
          acc[0][mt] = __builtin_amdgcn_mfma_f32_16x16x32_bf16(a, w2x[0][i], acc[0][mt], 0, 0, 0);
          acc[1][mt] = __builtin_amdgcn_mfma_f32_16x16x32_bf16(a, w2x[1][i], acc[1][mt], 0, 0, 0);
        }
      }
      epilogue(2, acc, hNew + 2L * kB * kH);
      arrive();
    }
  }

  // ===== final emitted row out[T-1]: FC from h2(T-2), block 0 only =====
  if (bid == 0 && T - 1 >= P && T >= 2) {
    // wait for every block's final arrival, then one acquire-inv
    {
      const int i = threadIdx.x;
      unsigned* fp = p.bflags + i * 32;
      for (;;) {
        unsigned v = (i < NBLK)
            ? __hip_atomic_load(fp, __ATOMIC_RELAXED, __HIP_MEMORY_SCOPE_AGENT)
            : bg;
        if (__syncthreads_and((int)(v >= bg))) break;
        __builtin_amdgcn_s_sleep(1);
      }
      if (tid == 0)
        (void)__hip_atomic_load(p.bflags, __ATOMIC_ACQUIRE, __HIP_MEMORY_SCOPE_AGENT);
      __syncthreads();
    }
    const u16* hL = ((T - 2) & 1) ? p.hA : p.hB;  // hNew of iteration T-2
    const u16* wfc_r = p.wbfc + (long)(w * 16 + colc) * kH + aoff;
    const u16* ap = hL + 2L * kB * kH + (long)colc * kH + aoff;
    f32x4 fa[4] = {z4, z4, z4, z4};
#pragma unroll 2
    for (int kk = 0; kk < 32; ++kk) {
      v8s b = *(const v8s*)(wfc_r + kk * 32);
#pragma unroll
      for (int mt = 0; mt < 4; ++mt) {
        v8s a = *(const v8s*)(ap + mt * 16 * kH + kk * 32);
        fa[mt] = __builtin_amdgcn_mfma_f32_16x16x32_bf16(a, b, fa[mt], 0, 0, 0);
      }
    }
    float bv = p.bfcs[w * 16 + colc];
    float* orow = p.out + (long)(T - 1) * (kB * kD);
#pragma unroll
    for (int mt = 0; mt < 4; ++mt)
#pragma unroll
      for (int r = 0; r < 4; ++r) {
        int bb = mt * 16 + kq * 4 + r, d = w * 16 + colc;
        st32(orow + (long)bb * kD + d, sigm(fa[mt][r] + bv));
      }
  }
}

extern "C" void kernel_launch(void* const* d_in, const int* in_sizes, int n_in,
                              void* d_out, int out_size, void* d_ws, size_t ws_size,
                              hipStream_t stream) {
  Params p;
  p.x   = (const float*)d_in[0];
  p.h0  = (const float*)d_in[1];
  p.c0  = (const float*)d_in[2];
  p.Wi0 = (const float*)d_in[3];
  p.Wh0 = (const float*)d_in[4];
  p.bi0 = (const float*)d_in[5];
  p.bh0 = (const float*)d_in[6];
  p.Wi1 = (const float*)d_in[7];
  p.Wh1 = (const float*)d_in[8];
  p.bi1 = (const float*)d_in[9];
  p.bh1 = (const float*)d_in[10];
  p.Wi2 = (const float*)d_in[11];
  p.Wh2 = (const float*)d_in[12];
  p.bi2 = (const float*)d_in[13];
  p.bh2 = (const float*)d_in[14];
  p.Wfc = (const float*)d_in[15];
  p.bfc = (const float*)d_in[16];
  p.out = (float*)d_out;
  p.P = in_sizes[0] / (kB * kD);
  p.T = out_size / (kB * kD);

  char* w = (char*)d_ws;
  auto alloc = [&](size_t bytes) {
    char* r = w;
    w += (bytes + 255) & ~(size_t)255;
    return r;
  };
  p.wb0i = (u16*)alloc(4096L * kD * 2);
  p.wb0h = (u16*)alloc(4096L * kH * 2);
  p.wb1i = (u16*)alloc(4096L * kH * 2);
  p.wb1h = (u16*)alloc(4096L * kH * 2);
  p.wb2i = (u16*)alloc(4096L * kH * 2);
  p.wb2h = (u16*)alloc(4096L * kH * 2);
  p.wbfc = (u16*)alloc((long)kD * kH * 2);
  p.xb   = (u16*)alloc((long)p.P * kB * kD * 2);
  p.hA   = (u16*)alloc((long)kL * kB * kH * 2);
  p.hB   = (u16*)alloc((long)kL * kB * kH * 2);
  p.curx = (u16*)alloc((long)kB * kD * 2);
  p.b0   = (float*)alloc(4096 * 4);
  p.b1   = (float*)alloc(4096 * 4);
  p.b2   = (float*)alloc(4096 * 4);
  p.bfcs = (float*)alloc(kD * 4);
  p.bflags = (unsigned*)alloc(NFLAG * 4);

  hipLaunchKernelGGL(init_kernel, dim3(512), dim3(256), 0, stream, p);
  void* args[] = { &p };
  hipLaunchCooperativeKernel((const void*)rnn_kernel, dim3(NBLK), dim3(NTHR),
                             args, 0, stream);
}

// Round 5
// 21789.870 us; speedup vs baseline: 2.1432x; 1.0921x over previous
//
#include <hip/hip_runtime.h>

typedef short v8s __attribute__((ext_vector_type(8)));
typedef float f32x4 __attribute__((ext_vector_type(4)));
typedef unsigned short u16;

static constexpr int kB = 64;    // batch
static constexpr int kH = 1024;  // hidden
static constexpr int kD = 128;   // input dim
static constexpr int kL = 3;     // layers
static constexpr int NBLK = 128; // proven cooperative grid size
static constexpr int NTHR = 512; // 8 waves
static constexpr int NFLAG = 16384;  // 3x128 layer-flag lines + 32 xflag lines

__device__ __forceinline__ u16 f2b(float f) {
  union { float f; unsigned u; } v; v.f = f;
  unsigned r = v.u + 0x7fffu + ((v.u >> 16) & 1u);
  return (u16)(r >> 16);
}

__device__ __forceinline__ float sigm(float x) { return 1.f / (1.f + expf(-x)); }

// Write-through stores: land at LLC (coherent point), leave no dirty L2 lines.
__device__ __forceinline__ void st16(u16* p, u16 v) {
  unsigned d = v;
  asm volatile("global_store_short %0, %1, off sc0 sc1" :: "v"(p), "v"(d) : "memory");
}
__device__ __forceinline__ void st32(float* p, float v) {
  asm volatile("global_store_dword %0, %1, off sc0 sc1" :: "v"(p), "v"(v) : "memory");
}
__device__ __forceinline__ void st32u(unsigned* p, unsigned v) {
  asm volatile("global_store_dword %0, %1, off sc0 sc1" :: "v"(p), "v"(v) : "memory");
}

struct Params {
  const float *x, *h0, *c0;
  const float *Wi0, *Wh0, *bi0, *bh0;
  const float *Wi1, *Wh1, *bi1, *bh1;
  const float *Wi2, *Wh2, *bi2, *bh2;
  const float *Wfc, *bfc;
  float *out;
  u16 *wb0i, *wb0h, *wb1i, *wb1h, *wb2i, *wb2h, *wbfc;
  u16 *xb, *hA, *hB, *curx;
  float *b0, *b1, *b2, *bfcs;
  unsigned *bflags;  // f0[128] | f1[128] | f2[128] | xflag[32] lines (x32 words)
  int P, T;
};

// ---------------- init: fp32 -> bf16 conversions, bias sums, state init ----
__global__ void init_kernel(Params p) {
  long gid = (long)blockIdx.x * blockDim.x + threadIdx.x;
  long stride = (long)gridDim.x * blockDim.x;
  const long nw0i = 4096L * kD, nwh = 4096L * kH, nfc = (long)kD * kH;
  for (long i = gid; i < nw0i; i += stride) p.wb0i[i] = f2b(p.Wi0[i]);
  for (long i = gid; i < nwh; i += stride) {
    p.wb0h[i] = f2b(p.Wh0[i]);
    p.wb1i[i] = f2b(p.Wi1[i]);
    p.wb1h[i] = f2b(p.Wh1[i]);
    p.wb2i[i] = f2b(p.Wi2[i]);
    p.wb2h[i] = f2b(p.Wh2[i]);
  }
  for (long i = gid; i < nfc; i += stride) p.wbfc[i] = f2b(p.Wfc[i]);
  for (long i = gid; i < 4096; i += stride) {
    p.b0[i] = p.bi0[i] + p.bh0[i];
    p.b1[i] = p.bi1[i] + p.bh1[i];
    p.b2[i] = p.bi2[i] + p.bh2[i];
  }
  for (long i = gid; i < kD; i += stride) p.bfcs[i] = p.bfc[i];
  for (long i = gid; i < NFLAG; i += stride) p.bflags[i] = 0u;  // flag state
  long nx = (long)p.P * kB * kD;
  for (long i = gid; i < nx; i += stride) {
    p.xb[i] = f2b(p.x[i]);
    p.out[i] = p.x[i];  // teacher-forced rows are exact copies
  }
  long nh = (long)kL * kB * kH;
  for (long i = gid; i < nh; i += stride) p.hA[i] = f2b(p.h0[i]);
}

// ---------------- persistent RNN: weights in VGPRs, stride-8 K retile ----
// Round-5 sync: SINGLE-HOP distributed flags. Per layer l, block b publishes
// f[l][b] = t+1 after (drain + sync) of its h_l(t) slice. Consumers poll the
// 128 producer flags DIRECTLY (wave 0, 2 lines/lane) -> one LLC hop, one
// max-jitter, no aggregator, no gen line. Polls start only after the h-part
// (data 3 phases old, wait-free), so they normally succeed in 1-2 iters —
// avoiding the round-1 poll-storm (which spun for whole phases).
// Transitive safety: each phase's x-wait on (prev layer flags >= t+1)
// guarantees all blocks completed their previous phase; this covers all h-part
// RAW deps and all WAR hazards on hA/hB/curx (writer's latest x-wait postdates
// every reader's flag publish). FC waits directly on f[2][*] >= t and runs at
// the TOP of phase A in its blocks (critical chain first).
__global__ void __launch_bounds__(NTHR) rnn_kernel(Params p) {
  const int tid = threadIdx.x, bid = blockIdx.x;
  const int lane = tid & 63, w = tid >> 6;  // 8 waves
  const int colc = lane & 15, kq = lane >> 4;
  const int aoff = kq * 8;
  const int u7 = colc & 7, gh = colc >> 3;
  const long wr0 = (long)gh * kH + bid * 8 + u7;        // gate-rows 0/1 tile
  const long wr1 = (long)(2 + gh) * kH + bid * 8 + u7;  // gate-rows 2/3 tile
  unsigned* f0arr = p.bflags;
  unsigned* f1arr = p.bflags + NBLK * 32;
  unsigned* f2arr = p.bflags + 2 * NBLK * 32;
  unsigned* xflag = p.bflags + 3 * NBLK * 32;  // 32 lines, one per FC wave

  // ---- one-time weight preload ----
  v8s w0x[2];  // waves 0-3 only: L0 x k-tile w
  v8s w0h[2][4], w1x[2][4], w1h[2][4], w2x[2][4], w2h[2][4];
  if (w < 4) {
    w0x[0] = *(const v8s*)(p.wb0i + wr0 * kD + w * 32 + aoff);
    w0x[1] = *(const v8s*)(p.wb0i + wr1 * kD + w * 32 + aoff);
  }
#pragma unroll
  for (int i = 0; i < 4; ++i) {
    int k = (w + 8 * i) * 32 + aoff;
    w0h[0][i] = *(const v8s*)(p.wb0h + wr0 * kH + k);
    w0h[1][i] = *(const v8s*)(p.wb0h + wr1 * kH + k);
    w1x[0][i] = *(const v8s*)(p.wb1i + wr0 * kH + k);
    w1x[1][i] = *(const v8s*)(p.wb1i + wr1 * kH + k);
    w1h[0][i] = *(const v8s*)(p.wb1h + wr0 * kH + k);
    w1h[1][i] = *(const v8s*)(p.wb1h + wr1 * kH + k);
    w2x[0][i] = *(const v8s*)(p.wb2i + wr0 * kH + k);
    w2x[1][i] = *(const v8s*)(p.wb2i + wr1 * kH + k);
    w2h[0][i] = *(const v8s*)(p.wb2h + wr0 * kH + k);
    w2h[1][i] = *(const v8s*)(p.wb2h + wr1 * kH + k);
  }

  // ---- per-thread cell state: 1 (batch, unit) cell per layer ----
  const int em = tid >> 3, eu = tid & 7;
  const int ehid = bid * 8 + eu;
  float cst[kL], brg[kL][4];
#pragma unroll
  for (int l = 0; l < kL; ++l)
    cst[l] = p.c0[(long)l * kB * kH + (long)em * kH + ehid];
  {
    const float* bp[3] = {p.b0, p.b1, p.b2};
#pragma unroll
    for (int l = 0; l < 3; ++l)
#pragma unroll
      for (int gg = 0; gg < 4; ++gg) brg[l][gg] = bp[l][gg * kH + ehid];
  }

  __shared__ float lg[8][64][18];  // stride 18: <=2-way bank aliasing
  const int T = p.T, P = p.P;
  const f32x4 z4 = {0.f, 0.f, 0.f, 0.f};

  auto epilogue = [&](int l, f32x4(&acc)[2][4], u16* hOut) {
    float pre[4];
#pragma unroll
    for (int mt = 0; mt < 4; ++mt)
#pragma unroll
      for (int r = 0; r < 4; ++r) lg[w][mt * 16 + kq * 4 + r][colc] = acc[0][mt][r];
    __syncthreads();
    {
      float s0 = 0.f, s1 = 0.f;
#pragma unroll
      for (int ww = 0; ww < 8; ++ww) {
        s0 += lg[ww][em][eu];
        s1 += lg[ww][em][8 + eu];
      }
      pre[0] = s0;
      pre[1] = s1;
    }
    __syncthreads();
#pragma unroll
    for (int mt = 0; mt < 4; ++mt)
#pragma unroll
      for (int r = 0; r < 4; ++r) lg[w][mt * 16 + kq * 4 + r][colc] = acc[1][mt][r];
    __syncthreads();
    {
      float s0 = 0.f, s1 = 0.f;
#pragma unroll
      for (int ww = 0; ww < 8; ++ww) {
        s0 += lg[ww][em][eu];
        s1 += lg[ww][em][8 + eu];
      }
      pre[2] = s0;
      pre[3] = s1;
    }
    float iv = pre[0] + brg[l][0], fv = pre[1] + brg[l][1];
    float gv = pre[2] + brg[l][2], ov = pre[3] + brg[l][3];
    float cn = sigm(fv) * cst[l] + sigm(iv) * tanhf(gv);
    cst[l] = cn;
    st16(hOut + (long)em * kH + ehid, f2b(sigm(ov) * tanhf(cn)));
  };

  // Arrival: per-wave drain -> block sync -> thread0 publishes layer flag.
  auto arrive = [&](unsigned* farr, unsigned val) {
    asm volatile("s_waitcnt vmcnt(0)" ::: "memory");
    __syncthreads();
    if (tid == 0) st32u(farr + bid * 32, val);
  };

  // x-wait: wave 0 polls all 128 producer flags (2/lane); block release;
  // single acquire-inv kills stale L1/L2 before the fresh reads.
  auto xwait = [&](unsigned* farr, unsigned tgt) {
    if (w == 0) {
      unsigned* fa = farr + lane * 32;
      unsigned* fb = farr + (64 + lane) * 32;
      for (;;) {
        unsigned a = __hip_atomic_load(fa, __ATOMIC_RELAXED, __HIP_MEMORY_SCOPE_AGENT);
        unsigned b = __hip_atomic_load(fb, __ATOMIC_RELAXED, __HIP_MEMORY_SCOPE_AGENT);
        if (__all((int)((a >= tgt) & (b >= tgt)))) break;
        __builtin_amdgcn_s_sleep(1);
      }
    }
    __syncthreads();
    if (tid == 0)
      (void)__hip_atomic_load(farr, __ATOMIC_ACQUIRE, __HIP_MEMORY_SCOPE_AGENT);
    __syncthreads();
  };

  for (int t = 0; t < T - 1; ++t) {
    const u16* hOld = (t & 1) ? p.hB : p.hA;
    u16* hNew = (t & 1) ? p.hA : p.hB;
    const bool genstep = (t >= P);
    const unsigned ft = (unsigned)(t + 1);

    // ================= phase A: (FC) + L0 =================
    {
      f32x4 acc[2][4] = {z4, z4, z4, z4, z4, z4, z4, z4};
      // FC producer FIRST (critical chain): blocks 0-7, waves 0-3.
      if (genstep && bid < 8 && w < 4) {
        const unsigned t2 = (unsigned)t;  // need f2 >= t (h2(t-1) ready)
        unsigned* fa = f2arr + lane * 32;
        unsigned* fb = f2arr + (64 + lane) * 32;
        for (;;) {
          unsigned a = __hip_atomic_load(fa, __ATOMIC_RELAXED, __HIP_MEMORY_SCOPE_AGENT);
          unsigned b = __hip_atomic_load(fb, __ATOMIC_RELAXED, __HIP_MEMORY_SCOPE_AGENT);
          if (__all((int)((a >= t2) & (b >= t2)))) break;
          __builtin_amdgcn_s_sleep(1);
        }
        (void)__hip_atomic_load(f2arr, __ATOMIC_ACQUIRE, __HIP_MEMORY_SCOPE_AGENT);
        f32x4 u0 = z4, u1 = z4;
        const u16* ap = hOld + 2L * kB * kH + (long)(w * 16 + colc) * kH + aoff;
        const u16* bp = p.wbfc + (long)(bid * 16 + colc) * kH + aoff;
#pragma unroll
        for (int i = 0; i < 16; ++i) {
          v8s a0 = *(const v8s*)(ap + i * 32);
          v8s b0 = *(const v8s*)(bp + i * 32);
          v8s a1 = *(const v8s*)(ap + 512 + i * 32);
          v8s b1 = *(const v8s*)(bp + 512 + i * 32);
          u0 = __builtin_amdgcn_mfma_f32_16x16x32_bf16(a0, b0, u0, 0, 0, 0);
          u1 = __builtin_amdgcn_mfma_f32_16x16x32_bf16(a1, b1, u1, 0, 0, 0);
        }
        float bv = p.bfcs[bid * 16 + colc];
#pragma unroll
        for (int r = 0; r < 4; ++r) {
          float val = sigm(u0[r] + u1[r] + bv);
          int bb = w * 16 + kq * 4 + r, d = bid * 16 + colc;
          st32(p.out + (long)t * (kB * kD) + (long)bb * kD + d, val);
          st16(p.curx + (long)bb * kD + d, f2b(val));
        }
        asm volatile("s_waitcnt vmcnt(0)" ::: "memory");  // curx tile visible
        if (lane == 0)
          st32u(xflag + (bid * 4 + w) * 32, (unsigned)(t - P + 1));
      }
      // h-part: 4 tiles/wave, data 3 phases old -> wait-free (transitive).
#pragma unroll
      for (int i = 0; i < 4; ++i) {
        int k = (w + 8 * i) * 32 + aoff;
#pragma unroll
        for (int mt = 0; mt < 4; ++mt) {
          v8s a = *(const v8s*)(hOld + (long)(mt * 16 + colc) * kH + k);
          acc[0][mt] = __builtin_amdgcn_mfma_f32_16x16x32_bf16(a, w0h[0][i], acc[0][mt], 0, 0, 0);
          acc[1][mt] = __builtin_amdgcn_mfma_f32_16x16x32_bf16(a, w0h[1][i], acc[1][mt], 0, 0, 0);
        }
      }
      // x-part: waves 0-3, one k-tile each.
      if (w < 4) {
        const u16* xin;
        if (genstep) {
          const unsigned tag = (unsigned)(t - P + 1);
          unsigned* xf = xflag + (lane & 31) * 32;
          for (;;) {
            unsigned v = (lane < 32)
                ? __hip_atomic_load(xf, __ATOMIC_RELAXED, __HIP_MEMORY_SCOPE_AGENT)
                : tag;
            if (__all((int)(v >= tag))) break;
            __builtin_amdgcn_s_sleep(1);
          }
          (void)__hip_atomic_load(xflag, __ATOMIC_ACQUIRE, __HIP_MEMORY_SCOPE_AGENT);
          xin = p.curx;
        } else {
          xin = p.xb + (long)t * kB * kD;
        }
        int k = w * 32 + aoff;
#pragma unroll
        for (int mt = 0; mt < 4; ++mt) {
          v8s a = *(const v8s*)(xin + (long)(mt * 16 + colc) * kD + k);
          acc[0][mt] = __builtin_amdgcn_mfma_f32_16x16x32_bf16(a, w0x[0], acc[0][mt], 0, 0, 0);
          acc[1][mt] = __builtin_amdgcn_mfma_f32_16x16x32_bf16(a, w0x[1], acc[1][mt], 0, 0, 0);
        }
      }
      epilogue(0, acc, hNew);
      arrive(f0arr, ft);
    }

    // ================= phase B: L1 =================
    {
      f32x4 acc[2][4] = {z4, z4, z4, z4, z4, z4, z4, z4};
      const u16* Ax = hNew;                      // h0(t): fresh, needs wait
      const u16* Ah = hOld + (long)kB * kH;      // h1(t-1): 3 phases old
#pragma unroll
      for (int i = 0; i < 4; ++i) {
        int k = (w + 8 * i) * 32 + aoff;
#pragma unroll
        for (int mt = 0; mt < 4; ++mt) {
          v8s a = *(const v8s*)(Ah + (long)(mt * 16 + colc) * kH + k);
          acc[0][mt] = __builtin_amdgcn_mfma_f32_16x16x32_bf16(a, w1h[0][i], acc[0][mt], 0, 0, 0);
          acc[1][mt] = __builtin_amdgcn_mfma_f32_16x16x32_bf16(a, w1h[1][i], acc[1][mt], 0, 0, 0);
        }
      }
      xwait(f0arr, ft);
#pragma unroll
      for (int i = 0; i < 4; ++i) {
        int k = (w + 8 * i) * 32 + aoff;
#pragma unroll
        for (int mt = 0; mt < 4; ++mt) {
          v8s a = *(const v8s*)(Ax + (long)(mt * 16 + colc) * kH + k);
          acc[0][mt] = __builtin_amdgcn_mfma_f32_16x16x32_bf16(a, w1x[0][i], acc[0][mt], 0, 0, 0);
          acc[1][mt] = __builtin_amdgcn_mfma_f32_16x16x32_bf16(a, w1x[1][i], acc[1][mt], 0, 0, 0);
        }
      }
      epilogue(1, acc, hNew + (long)kB * kH);
      arrive(f1arr, ft);
    }

    // ================= phase C: L2 =================
    {
      f32x4 acc[2][4] = {z4, z4, z4, z4, z4, z4, z4, z4};
      const u16* Ax = hNew + (long)kB * kH;      // h1(t): fresh, needs wait
      const u16* Ah = hOld + 2L * kB * kH;       // h2(t-1): 3 phases old
#pragma unroll
      for (int i = 0; i < 4; ++i) {
        int k = (w + 8 * i) * 32 + aoff;
#pragma unroll
        for (int mt = 0; mt < 4; ++mt) {
          v8s a = *(const v8s*)(Ah + (long)(mt * 16 + colc) * kH + k);
          acc[0][mt] = __builtin_amdgcn_mfma_f32_16x16x32_bf16(a, w2h[0][i], acc[0][mt], 0, 0, 0);
          acc[1][mt] = __builtin_amdgcn_mfma_f32_16x16x32_bf16(a, w2h[1][i], acc[1][mt], 0, 0, 0);
        }
      }
      xwait(f1arr, ft);
#pragma unroll
      for (int i = 0; i < 4; ++i) {
        int k = (w + 8 * i) * 32 + aoff;
#pragma unroll
        for (int mt = 0; mt < 4; ++mt) {
          v8s a = *(const v8s*)(Ax + (long)(mt * 16 + colc) * kH + k);
          acc[0][mt] = __builtin_amdgcn_mfma_f32_16x16x32_bf16(a, w2x[0][i], acc[0][mt], 0, 0, 0);
          acc[1][mt] = __builtin_amdgcn_mfma_f32_16x16x32_bf16(a, w2x[1][i], acc[1][mt], 0, 0, 0);
        }
      }
      epilogue(2, acc, hNew + 2L * kB * kH);
      arrive(f2arr, ft);
    }
  }

  // ===== final emitted row out[T-1]: FC from h2(T-2), block 0 only =====
  if (bid == 0 && T - 1 >= P && T >= 2) {
    const unsigned tgt = (unsigned)(T - 1);  // f2 after last C = T-1
    {
      const int i = threadIdx.x;
      unsigned* fp = f2arr + i * 32;
      for (;;) {
        unsigned v = (i < NBLK)
            ? __hip_atomic_load(fp, __ATOMIC_RELAXED, __HIP_MEMORY_SCOPE_AGENT)
            : tgt;
        if (__syncthreads_and((int)(v >= tgt))) break;
        __builtin_amdgcn_s_sleep(1);
      }
      if (tid == 0)
        (void)__hip_atomic_load(f2arr, __ATOMIC_ACQUIRE, __HIP_MEMORY_SCOPE_AGENT);
      __syncthreads();
    }
    const u16* hL = ((T - 2) & 1) ? p.hA : p.hB;  // hNew of iteration T-2
    const u16* wfc_r = p.wbfc + (long)(w * 16 + colc) * kH + aoff;
    const u16* ap = hL + 2L * kB * kH + (long)colc * kH + aoff;
    f32x4 fa[4] = {z4, z4, z4, z4};
#pragma unroll 2
    for (int kk = 0; kk < 32; ++kk) {
      v8s b = *(const v8s*)(wfc_r + kk * 32);
#pragma unroll
      for (int mt = 0; mt < 4; ++mt) {
        v8s a = *(const v8s*)(ap + mt * 16 * kH + kk * 32);
        fa[mt] = __builtin_amdgcn_mfma_f32_16x16x32_bf16(a, b, fa[mt], 0, 0, 0);
      }
    }
    float bv = p.bfcs[w * 16 + colc];
    float* orow = p.out + (long)(T - 1) * (kB * kD);
#pragma unroll
    for (int mt = 0; mt < 4; ++mt)
#pragma unroll
      for (int r = 0; r < 4; ++r) {
        int bb = mt * 16 + kq * 4 + r, d = w * 16 + colc;
        st32(orow + (long)bb * kD + d, sigm(fa[mt][r] + bv));
      }
  }
}

extern "C" void kernel_launch(void* const* d_in, const int* in_sizes, int n_in,
                              void* d_out, int out_size, void* d_ws, size_t ws_size,
                              hipStream_t stream) {
  Params p;
  p.x   = (const float*)d_in[0];
  p.h0  = (const float*)d_in[1];
  p.c0  = (const float*)d_in[2];
  p.Wi0 = (const float*)d_in[3];
  p.Wh0 = (const float*)d_in[4];
  p.bi0 = (const float*)d_in[5];
  p.bh0 = (const float*)d_in[6];
  p.Wi1 = (const float*)d_in[7];
  p.Wh1 = (const float*)d_in[8];
  p.bi1 = (const float*)d_in[9];
  p.bh1 = (const float*)d_in[10];
  p.Wi2 = (const float*)d_in[11];
  p.Wh2 = (const float*)d_in[12];
  p.bi2 = (const float*)d_in[13];
  p.bh2 = (const float*)d_in[14];
  p.Wfc = (const float*)d_in[15];
  p.bfc = (const float*)d_in[16];
  p.out = (float*)d_out;
  p.P = in_sizes[0] / (kB * kD);
  p.T = out_size / (kB * kD);

  char* w = (char*)d_ws;
  auto alloc = [&](size_t bytes) {
    char* r = w;
    w += (bytes + 255) & ~(size_t)255;
    return r;
  };
  p.wb0i = (u16*)alloc(4096L * kD * 2);
  p.wb0h = (u16*)alloc(4096L * kH * 2);
  p.wb1i = (u16*)alloc(4096L * kH * 2);
  p.wb1h = (u16*)alloc(4096L * kH * 2);
  p.wb2i = (u16*)alloc(4096L * kH * 2);
  p.wb2h = (u16*)alloc(4096L * kH * 2);
  p.wbfc = (u16*)alloc((long)kD * kH * 2);
  p.xb   = (u16*)alloc((long)p.P * kB * kD * 2);
  p.hA   = (u16*)alloc((long)kL * kB * kH * 2);
  p.hB   = (u16*)alloc((long)kL * kB * kH * 2);
  p.curx = (u16*)alloc((long)kB * kD * 2);
  p.b0   = (float*)alloc(4096 * 4);
  p.b1   = (float*)alloc(4096 * 4);
  p.b2   = (float*)alloc(4096 * 4);
  p.bfcs = (float*)alloc(kD * 4);
  p.bflags = (unsigned*)alloc(NFLAG * 4);

  hipLaunchKernelGGL(init_kernel, dim3(512), dim3(256), 0, stream, p);
  void* args[] = { &p };
  hipLaunchCooperativeKernel((const void*)rnn_kernel, dim3(NBLK), dim3(NTHR),
                             args, 0, stream);
}

// Round 6
// 19535.602 us; speedup vs baseline: 2.3906x; 1.1154x over previous
//
#include <hip/hip_runtime.h>

typedef short v8s __attribute__((ext_vector_type(8)));
typedef float f32x4 __attribute__((ext_vector_type(4)));
typedef unsigned short u16;

static constexpr int kB = 64;    // batch
static constexpr int kH = 1024;  // hidden
static constexpr int kD = 128;   // input dim
static constexpr int kL = 3;     // layers
static constexpr int NBLK = 128; // proven cooperative grid size
static constexpr int NTHR = 512; // 8 waves
static constexpr int NFLAG = 16384;  // 3x128 layer-flag lines + 32 xflag lines

__device__ __forceinline__ u16 f2b(float f) {
  union { float f; unsigned u; } v; v.f = f;
  unsigned r = v.u + 0x7fffu + ((v.u >> 16) & 1u);
  return (u16)(r >> 16);
}

__device__ __forceinline__ float sigm(float x) { return 1.f / (1.f + expf(-x)); }

// Write-through stores: land at LLC (coherent point), leave no dirty L2 lines.
__device__ __forceinline__ void st16(u16* p, u16 v) {
  unsigned d = v;
  asm volatile("global_store_short %0, %1, off sc0 sc1" :: "v"(p), "v"(d) : "memory");
}
__device__ __forceinline__ void st32(float* p, float v) {
  asm volatile("global_store_dword %0, %1, off sc0 sc1" :: "v"(p), "v"(v) : "memory");
}
__device__ __forceinline__ void st32u(unsigned* p, unsigned v) {
  asm volatile("global_store_dword %0, %1, off sc0 sc1" :: "v"(p), "v"(v) : "memory");
}

// Cache-BYPASS 16B loads (sc0 sc1: read at LLC, never fill L1/L2). Used for
// all mutable data (h slabs, curx) -> no acquire-inv needed anywhere on the
// consumer path. Explicit vmcnt + sched_barrier discipline (guide rule #18).
__device__ __forceinline__ void ld4cv(v8s& a0, v8s& a1, v8s& a2, v8s& a3,
                                      const u16* p0, const u16* p1,
                                      const u16* p2, const u16* p3) {
  asm volatile(
      "global_load_dwordx4 %0, %4, off sc0 sc1\n\t"
      "global_load_dwordx4 %1, %5, off sc0 sc1\n\t"
      "global_load_dwordx4 %2, %6, off sc0 sc1\n\t"
      "global_load_dwordx4 %3, %7, off sc0 sc1"
      : "=&v"(a0), "=&v"(a1), "=&v"(a2), "=&v"(a3)
      : "v"(p0), "v"(p1), "v"(p2), "v"(p3)
      : "memory");
}
#define WAITV(N) do { asm volatile("s_waitcnt vmcnt(" #N ")" ::: "memory"); \
                      __builtin_amdgcn_sched_barrier(0); } while (0)
#define MFMA8(A, W, I, ACC) do { \
  _Pragma("unroll") \
  for (int mt_ = 0; mt_ < 4; ++mt_) { \
    ACC[0][mt_] = __builtin_amdgcn_mfma_f32_16x16x32_bf16(A[mt_], W[0][I], ACC[0][mt_], 0, 0, 0); \
    ACC[1][mt_] = __builtin_amdgcn_mfma_f32_16x16x32_bf16(A[mt_], W[1][I], ACC[1][mt_], 0, 0, 0); \
  } } while (0)

struct Params {
  const float *x, *h0, *c0;
  const float *Wi0, *Wh0, *bi0, *bh0;
  const float *Wi1, *Wh1, *bi1, *bh1;
  const float *Wi2, *Wh2, *bi2, *bh2;
  const float *Wfc, *bfc;
  float *out;
  u16 *wb0i, *wb0h, *wb1i, *wb1h, *wb2i, *wb2h, *wbfc;
  u16 *xb, *hA, *hB, *curx;
  float *b0, *b1, *b2, *bfcs;
  unsigned *bflags;  // f0[128] | f1[128] | f2[128] | xflag[32] lines (x32 words)
  int P, T;
};

// ---------------- init: fp32 -> bf16 conversions, bias sums, state init ----
__global__ void init_kernel(Params p) {
  long gid = (long)blockIdx.x * blockDim.x + threadIdx.x;
  long stride = (long)gridDim.x * blockDim.x;
  const long nw0i = 4096L * kD, nwh = 4096L * kH, nfc = (long)kD * kH;
  for (long i = gid; i < nw0i; i += stride) p.wb0i[i] = f2b(p.Wi0[i]);
  for (long i = gid; i < nwh; i += stride) {
    p.wb0h[i] = f2b(p.Wh0[i]);
    p.wb1i[i] = f2b(p.Wi1[i]);
    p.wb1h[i] = f2b(p.Wh1[i]);
    p.wb2i[i] = f2b(p.Wi2[i]);
    p.wb2h[i] = f2b(p.Wh2[i]);
  }
  for (long i = gid; i < nfc; i += stride) p.wbfc[i] = f2b(p.Wfc[i]);
  for (long i = gid; i < 4096; i += stride) {
    p.b0[i] = p.bi0[i] + p.bh0[i];
    p.b1[i] = p.bi1[i] + p.bh1[i];
    p.b2[i] = p.bi2[i] + p.bh2[i];
  }
  for (long i = gid; i < kD; i += stride) p.bfcs[i] = p.bfc[i];
  for (long i = gid; i < NFLAG; i += stride) p.bflags[i] = 0u;  // flag state
  long nx = (long)p.P * kB * kD;
  for (long i = gid; i < nx; i += stride) {
    p.xb[i] = f2b(p.x[i]);
    p.out[i] = p.x[i];  // teacher-forced rows are exact copies
  }
  long nh = (long)kL * kB * kH;
  for (long i = gid; i < nh; i += stride) p.hA[i] = f2b(p.h0[i]);
}

// ---------------- persistent RNN: wave-level dataflow ----
// Round-6 sync: the k-tile mapping {w+8i} is IDENTICAL in every phase, so
// wave w's x-part at any phase reads exactly the h units of blocks
// 4(w+8i)+{0..3} — the same 16 blocks it polls. Per-wave 16-flag waits
// (8 xflags for phase A), NO block-wide join before the x-part, NO cache
// invalidates: all h/curx reads are sc0sc1 bypass loads straight from the
// LLC where the write-through publishes land.
// Certification chains (per-wave, set = its 16 blocks):
//   A(t) h0(t-1): certified by this wave's B(t-1) poll of f0(t-1) (same set).
//   B(t) h1(t-1): certified by C(t-1) poll of f1(t-1).
//   C(t) h2(t-1): certified by B(t) poll of f0(t) (f0(t) postdates f2(t-1)).
//   A(t) curx(t): xflag poll (8 producer FC-waves for this wave's d-tile).
// WAR: each block's 8 waves' poll-union covers all 128 blocks every phase,
// joined by the epilogue syncthreads -> any writer transitively postdates
// all readers of the slab it overwrites (2 steps old).
__global__ void __launch_bounds__(NTHR) rnn_kernel(Params p) {
  const int tid = threadIdx.x, bid = blockIdx.x;
  const int lane = tid & 63, w = tid >> 6;  // 8 waves
  const int colc = lane & 15, kq = lane >> 4;
  const int aoff = kq * 8;
  const int u7 = colc & 7, gh = colc >> 3;
  const long wr0 = (long)gh * kH + bid * 8 + u7;        // gate-rows 0/1 tile
  const long wr1 = (long)(2 + gh) * kH + bid * 8 + u7;  // gate-rows 2/3 tile
  unsigned* f0arr = p.bflags;
  unsigned* f1arr = p.bflags + NBLK * 32;
  unsigned* f2arr = p.bflags + 2 * NBLK * 32;
  unsigned* xflag = p.bflags + 3 * NBLK * 32;  // 32 lines, one per FC wave

  // ---- one-time weight preload ----
  v8s w0x[2];  // waves 0-3 only: L0 x k-tile w
  v8s w0h[2][4], w1x[2][4], w1h[2][4], w2x[2][4], w2h[2][4];
  if (w < 4) {
    w0x[0] = *(const v8s*)(p.wb0i + wr0 * kD + w * 32 + aoff);
    w0x[1] = *(const v8s*)(p.wb0i + wr1 * kD + w * 32 + aoff);
  }
#pragma unroll
  for (int i = 0; i < 4; ++i) {
    int k = (w + 8 * i) * 32 + aoff;
    w0h[0][i] = *(const v8s*)(p.wb0h + wr0 * kH + k);
    w0h[1][i] = *(const v8s*)(p.wb0h + wr1 * kH + k);
    w1x[0][i] = *(const v8s*)(p.wb1i + wr0 * kH + k);
    w1x[1][i] = *(const v8s*)(p.wb1i + wr1 * kH + k);
    w1h[0][i] = *(const v8s*)(p.wb1h + wr0 * kH + k);
    w1h[1][i] = *(const v8s*)(p.wb1h + wr1 * kH + k);
    w2x[0][i] = *(const v8s*)(p.wb2i + wr0 * kH + k);
    w2x[1][i] = *(const v8s*)(p.wb2i + wr1 * kH + k);
    w2h[0][i] = *(const v8s*)(p.wb2h + wr0 * kH + k);
    w2h[1][i] = *(const v8s*)(p.wb2h + wr1 * kH + k);
  }

  // ---- per-thread cell state: 1 (batch, unit) cell per layer ----
  const int em = tid >> 3, eu = tid & 7;
  const int ehid = bid * 8 + eu;
  float cst[kL], brg[kL][4];
#pragma unroll
  for (int l = 0; l < kL; ++l)
    cst[l] = p.c0[(long)l * kB * kH + (long)em * kH + ehid];
  {
    const float* bp[3] = {p.b0, p.b1, p.b2};
#pragma unroll
    for (int l = 0; l < 3; ++l)
#pragma unroll
      for (int gg = 0; gg < 4; ++gg) brg[l][gg] = bp[l][gg * kH + ehid];
  }

  __shared__ float lg[8][64][18];  // stride 18: <=2-way bank aliasing
  const int T = p.T, P = p.P;
  const f32x4 z4 = {0.f, 0.f, 0.f, 0.f};

  auto epilogue = [&](int l, f32x4(&acc)[2][4], u16* hOut) {
    float pre[4];
#pragma unroll
    for (int mt = 0; mt < 4; ++mt)
#pragma unroll
      for (int r = 0; r < 4; ++r) lg[w][mt * 16 + kq * 4 + r][colc] = acc[0][mt][r];
    __syncthreads();
    {
      float s0 = 0.f, s1 = 0.f;
#pragma unroll
      for (int ww = 0; ww < 8; ++ww) {
        s0 += lg[ww][em][eu];
        s1 += lg[ww][em][8 + eu];
      }
      pre[0] = s0;
      pre[1] = s1;
    }
    __syncthreads();
#pragma unroll
    for (int mt = 0; mt < 4; ++mt)
#pragma unroll
      for (int r = 0; r < 4; ++r) lg[w][mt * 16 + kq * 4 + r][colc] = acc[1][mt][r];
    __syncthreads();
    {
      float s0 = 0.f, s1 = 0.f;
#pragma unroll
      for (int ww = 0; ww < 8; ++ww) {
        s0 += lg[ww][em][eu];
        s1 += lg[ww][em][8 + eu];
      }
      pre[2] = s0;
      pre[3] = s1;
    }
    float iv = pre[0] + brg[l][0], fv = pre[1] + brg[l][1];
    float gv = pre[2] + brg[l][2], ov = pre[3] + brg[l][3];
    float cn = sigm(fv) * cst[l] + sigm(iv) * tanhf(gv);
    cst[l] = cn;
    st16(hOut + (long)em * kH + ehid, f2b(sigm(ov) * tanhf(cn)));
  };

  // Arrival: per-wave drain -> block sync -> thread0 publishes layer flag.
  auto arrive = [&](unsigned* farr, unsigned val) {
    asm volatile("s_waitcnt vmcnt(0)" ::: "memory");
    __syncthreads();
    if (tid == 0) st32u(farr + bid * 32, val);
  };

  // Per-wave poll of this wave's 16 producer blocks (k-tiles {w+8i}).
  auto poll16 = [&](unsigned* farr, unsigned tgt) {
    unsigned* fp = farr + (4 * (w + 8 * (lane >> 2)) + (lane & 3)) * 32;
    for (;;) {
      unsigned v = (lane < 16)
          ? __hip_atomic_load(fp, __ATOMIC_RELAXED, __HIP_MEMORY_SCOPE_AGENT)
          : tgt;
      if (__all((int)(v >= tgt))) break;
      __builtin_amdgcn_s_sleep(1);
    }
    asm volatile("" ::: "memory");  // no loads hoisted above the poll
  };

  // Bypass-load GEMM over 4 k-tiles {w+8i}: 2-deep pipelined 4-load batches.
  auto gemm16 = [&](const u16* Ab, v8s (&W)[2][4], f32x4 (&acc)[2][4]) {
    const u16* b0 = Ab + (long)colc * kH + w * 32 + aoff;
    const u16* b1 = b0 + 16 * kH;
    const u16* b2 = b0 + 32 * kH;
    const u16* b3 = b0 + 48 * kH;
    v8s A0[4], A1[4], A2[4], A3[4];
    ld4cv(A0[0], A0[1], A0[2], A0[3], b0, b1, b2, b3);
    ld4cv(A1[0], A1[1], A1[2], A1[3], b0 + 256, b1 + 256, b2 + 256, b3 + 256);
    WAITV(4);
    MFMA8(A0, W, 0, acc);
    ld4cv(A2[0], A2[1], A2[2], A2[3], b0 + 512, b1 + 512, b2 + 512, b3 + 512);
    WAITV(4);
    MFMA8(A1, W, 1, acc);
    ld4cv(A3[0], A3[1], A3[2], A3[3], b0 + 768, b1 + 768, b2 + 768, b3 + 768);
    WAITV(4);
    MFMA8(A2, W, 2, acc);
    WAITV(0);
    MFMA8(A3, W, 3, acc);
  };

  for (int t = 0; t < T - 1; ++t) {
    const u16* hOld = (t & 1) ? p.hB : p.hA;
    u16* hNew = (t & 1) ? p.hA : p.hB;
    const bool genstep = (t >= P);
    const unsigned ft = (unsigned)(t + 1);

    // ================= phase A: (FC) + L0 =================
    {
      f32x4 acc[2][4] = {z4, z4, z4, z4, z4, z4, z4, z4};
      // FC producer FIRST (critical chain): blocks 0-7, waves 0-3. Full-K
      // read -> polls all 128 f2 flags; CACHED loads + private acquire-inv.
      if (genstep && bid < 8 && w < 4) {
        const unsigned t2 = (unsigned)t;  // need f2 >= t (h2(t-1) ready)
        unsigned* fa = f2arr + lane * 32;
        unsigned* fb = f2arr + (64 + lane) * 32;
        for (;;) {
          unsigned a = __hip_atomic_load(fa, __ATOMIC_RELAXED, __HIP_MEMORY_SCOPE_AGENT);
          unsigned b = __hip_atomic_load(fb, __ATOMIC_RELAXED, __HIP_MEMORY_SCOPE_AGENT);
          if (__all((int)((a >= t2) & (b >= t2)))) break;
          __builtin_amdgcn_s_sleep(1);
        }
        (void)__hip_atomic_load(f2arr, __ATOMIC_ACQUIRE, __HIP_MEMORY_SCOPE_AGENT);
        f32x4 u0 = z4, u1 = z4;
        const u16* ap = hOld + 2L * kB * kH + (long)(w * 16 + colc) * kH + aoff;
        const u16* bp = p.wbfc + (long)(bid * 16 + colc) * kH + aoff;
#pragma unroll
        for (int i = 0; i < 16; ++i) {
          v8s a0 = *(const v8s*)(ap + i * 32);
          v8s b0 = *(const v8s*)(bp + i * 32);
          v8s a1 = *(const v8s*)(ap + 512 + i * 32);
          v8s b1 = *(const v8s*)(bp + 512 + i * 32);
          u0 = __builtin_amdgcn_mfma_f32_16x16x32_bf16(a0, b0, u0, 0, 0, 0);
          u1 = __builtin_amdgcn_mfma_f32_16x16x32_bf16(a1, b1, u1, 0, 0, 0);
        }
        float bv = p.bfcs[bid * 16 + colc];
#pragma unroll
        for (int r = 0; r < 4; ++r) {
          float val = sigm(u0[r] + u1[r] + bv);
          int bb = w * 16 + kq * 4 + r, d = bid * 16 + colc;
          st32(p.out + (long)t * (kB * kD) + (long)bb * kD + d, val);
          st16(p.curx + (long)bb * kD + d, f2b(val));
        }
        asm volatile("s_waitcnt vmcnt(0)" ::: "memory");  // curx tile visible
        if (lane == 0)
          st32u(xflag + (bid * 4 + w) * 32, (unsigned)(t - P + 1));
      }
      // h-part: wait-free (certified by this wave's B(t-1) poll of f0(t-1)).
      gemm16(hOld, w0h, acc);
      // x-part: waves 0-3, one k-tile each.
      if (w < 4) {
        if (genstep) {
          // 8 producer FC-waves for d-tile w: bidp in {2w,2w+1} x wp 0..3
          const unsigned tag = (unsigned)(t - P + 1);
          unsigned* fp = xflag + ((2 * w + (lane >> 2)) * 4 + (lane & 3)) * 32;
          for (;;) {
            unsigned v = (lane < 8)
                ? __hip_atomic_load(fp, __ATOMIC_RELAXED, __HIP_MEMORY_SCOPE_AGENT)
                : tag;
            if (__all((int)(v >= tag))) break;
            __builtin_amdgcn_s_sleep(1);
          }
          asm volatile("" ::: "memory");
          const u16* xb0 = p.curx + (long)colc * kD + w * 32 + aoff;
          v8s X[4];
          ld4cv(X[0], X[1], X[2], X[3],
                xb0, xb0 + 16 * kD, xb0 + 32 * kD, xb0 + 48 * kD);
          WAITV(0);
#pragma unroll
          for (int mt = 0; mt < 4; ++mt) {
            acc[0][mt] = __builtin_amdgcn_mfma_f32_16x16x32_bf16(X[mt], w0x[0], acc[0][mt], 0, 0, 0);
            acc[1][mt] = __builtin_amdgcn_mfma_f32_16x16x32_bf16(X[mt], w0x[1], acc[1][mt], 0, 0, 0);
          }
        } else {
          const u16* xin = p.xb + (long)t * kB * kD;
          int k = w * 32 + aoff;
#pragma unroll
          for (int mt = 0; mt < 4; ++mt) {
            v8s a = *(const v8s*)(xin + (long)(mt * 16 + colc) * kD + k);
            acc[0][mt] = __builtin_amdgcn_mfma_f32_16x16x32_bf16(a, w0x[0], acc[0][mt], 0, 0, 0);
            acc[1][mt] = __builtin_amdgcn_mfma_f32_16x16x32_bf16(a, w0x[1], acc[1][mt], 0, 0, 0);
          }
        }
      }
      epilogue(0, acc, hNew);
      arrive(f0arr, ft);
    }

    // ================= phase B: L1 =================
    {
      f32x4 acc[2][4] = {z4, z4, z4, z4, z4, z4, z4, z4};
      // h-part h1(t-1): certified by this wave's C(t-1) poll of f1(t-1).
      gemm16(hOld + (long)kB * kH, w1h, acc);
      // x-part h0(t): per-wave 16-flag wait, then bypass loads.
      poll16(f0arr, ft);
      gemm16(hNew, w1x, acc);
      epilogue(1, acc, hNew + (long)kB * kH);
      arrive(f1arr, ft);
    }

    // ================= phase C: L2 =================
    {
      f32x4 acc[2][4] = {z4, z4, z4, z4, z4, z4, z4, z4};
      // h-part h2(t-1): certified by this wave's B(t) poll of f0(t)
      // (block c publishes f0(t) only after its C(t-1) h2 drain).
      gemm16(hOld + 2L * kB * kH, w2h, acc);
      // x-part h1(t): per-wave 16-flag wait.
      poll16(f1arr, ft);
      gemm16(hNew + (long)kB * kH, w2x, acc);
      epilogue(2, acc, hNew + 2L * kB * kH);
      arrive(f2arr, ft);
    }
  }

  // ===== final emitted row out[T-1]: FC from h2(T-2), block 0 only =====
  if (bid == 0 && T - 1 >= P && T >= 2) {
    const unsigned tgt = (unsigned)(T - 1);  // f2 after last C = T-1
    {
      const int i = threadIdx.x;
      unsigned* fp = f2arr + i * 32;
      for (;;) {
        unsigned v = (i < NBLK)
            ? __hip_atomic_load(fp, __ATOMIC_RELAXED, __HIP_MEMORY_SCOPE_AGENT)
            : tgt;
        if (__syncthreads_and((int)(v >= tgt))) break;
        __builtin_amdgcn_s_sleep(1);
      }
      if (tid == 0)
        (void)__hip_atomic_load(f2arr, __ATOMIC_ACQUIRE, __HIP_MEMORY_SCOPE_AGENT);
      __syncthreads();
    }
    const u16* hL = ((T - 2) & 1) ? p.hA : p.hB;  // hNew of iteration T-2
    const u16* wfc_r = p.wbfc + (long)(w * 16 + colc) * kH + aoff;
    const u16* ap = hL + 2L * kB * kH + (long)colc * kH + aoff;
    f32x4 fa[4] = {z4, z4, z4, z4};
#pragma unroll 2
    for (int kk = 0; kk < 32; ++kk) {
      v8s b = *(const v8s*)(wfc_r + kk * 32);
#pragma unroll
      for (int mt = 0; mt < 4; ++mt) {
        v8s a = *(const v8s*)(ap + mt * 16 * kH + kk * 32);
        fa[mt] = __builtin_amdgcn_mfma_f32_16x16x32_bf16(a, b, fa[mt], 0, 0, 0);
      }
    }
    float bv = p.bfcs[w * 16 + colc];
    float* orow = p.out + (long)(T - 1) * (kB * kD);
#pragma unroll
    for (int mt = 0; mt < 4; ++mt)
#pragma unroll
      for (int r = 0; r < 4; ++r) {
        int bb = mt * 16 + kq * 4 + r, d = w * 16 + colc;
        st32(orow + (long)bb * kD + d, sigm(fa[mt][r] + bv));
      }
  }
}

extern "C" void kernel_launch(void* const* d_in, const int* in_sizes, int n_in,
                              void* d_out, int out_size, void* d_ws, size_t ws_size,
                              hipStream_t stream) {
  Params p;
  p.x   = (const float*)d_in[0];
  p.h0  = (const float*)d_in[1];
  p.c0  = (const float*)d_in[2];
  p.Wi0 = (const float*)d_in[3];
  p.Wh0 = (const float*)d_in[4];
  p.bi0 = (const float*)d_in[5];
  p.bh0 = (const float*)d_in[6];
  p.Wi1 = (const float*)d_in[7];
  p.Wh1 = (const float*)d_in[8];
  p.bi1 = (const float*)d_in[9];
  p.bh1 = (const float*)d_in[10];
  p.Wi2 = (const float*)d_in[11];
  p.Wh2 = (const float*)d_in[12];
  p.bi2 = (const float*)d_in[13];
  p.bh2 = (const float*)d_in[14];
  p.Wfc = (const float*)d_in[15];
  p.bfc = (const float*)d_in[16];
  p.out = (float*)d_out;
  p.P = in_sizes[0] / (kB * kD);
  p.T = out_size / (kB * kD);

  char* w = (char*)d_ws;
  auto alloc = [&](size_t bytes) {
    char* r = w;
    w += (bytes + 255) & ~(size_t)255;
    return r;
  };
  p.wb0i = (u16*)alloc(4096L * kD * 2);
  p.wb0h = (u16*)alloc(4096L * kH * 2);
  p.wb1i = (u16*)alloc(4096L * kH * 2);
  p.wb1h = (u16*)alloc(4096L * kH * 2);
  p.wb2i = (u16*)alloc(4096L * kH * 2);
  p.wb2h = (u16*)alloc(4096L * kH * 2);
  p.wbfc = (u16*)alloc((long)kD * kH * 2);
  p.xb   = (u16*)alloc((long)p.P * kB * kD * 2);
  p.hA   = (u16*)alloc((long)kL * kB * kH * 2);
  p.hB   = (u16*)alloc((long)kL * kB * kH * 2);
  p.curx = (u16*)alloc((long)kB * kD * 2);
  p.b0   = (float*)alloc(4096 * 4);
  p.b1   = (float*)alloc(4096 * 4);
  p.b2   = (float*)alloc(4096 * 4);
  p.bfcs = (float*)alloc(kD * 4);
  p.bflags = (unsigned*)alloc(NFLAG * 4);

  hipLaunchKernelGGL(init_kernel, dim3(512), dim3(256), 0, stream, p);
  void* args[] = { &p };
  hipLaunchCooperativeKernel((const void*)rnn_kernel, dim3(NBLK), dim3(NTHR),
                             args, 0, stream);
}

// Round 7
// 17113.507 us; speedup vs baseline: 2.7289x; 1.1415x over previous
//
#include <hip/hip_runtime.h>

typedef short v8s __attribute__((ext_vector_type(8)));
typedef float f32x4 __attribute__((ext_vector_type(4)));
typedef unsigned short u16;

static constexpr int kB = 64;    // batch
static constexpr int kH = 1024;  // hidden
static constexpr int kD = 128;   // input dim
static constexpr int kL = 3;     // layers
static constexpr int NBLK = 128; // LSTM blocks (hidden partition)
static constexpr int NFC = 8;    // dedicated FC blocks
static constexpr int NBLK_TOT = NBLK + NFC;  // 136 <= 256 CUs
static constexpr int NTHR = 512; // 8 waves
static constexpr int NFLAG = 16384;  // 3x128 layer-flag lines + 32 xflag lines

__device__ __forceinline__ u16 f2b(float f) {
  union { float f; unsigned u; } v; v.f = f;
  unsigned r = v.u + 0x7fffu + ((v.u >> 16) & 1u);
  return (u16)(r >> 16);
}

__device__ __forceinline__ float sigm(float x) { return 1.f / (1.f + expf(-x)); }

// Write-through stores: land at LLC (coherent point), leave no dirty L2 lines.
__device__ __forceinline__ void st16(u16* p, u16 v) {
  unsigned d = v;
  asm volatile("global_store_short %0, %1, off sc0 sc1" :: "v"(p), "v"(d) : "memory");
}
__device__ __forceinline__ void st32(float* p, float v) {
  asm volatile("global_store_dword %0, %1, off sc0 sc1" :: "v"(p), "v"(v) : "memory");
}
__device__ __forceinline__ void st32u(unsigned* p, unsigned v) {
  asm volatile("global_store_dword %0, %1, off sc0 sc1" :: "v"(p), "v"(v) : "memory");
}
__device__ __forceinline__ void st128(u16* p, v8s v) {
  asm volatile("global_store_dwordx4 %0, %1, off sc0 sc1" :: "v"(p), "v"(v) : "memory");
}

// Cache-BYPASS 16B loads (sc0 sc1: read at LLC, never fill L1/L2). Used for
// all mutable data (h slabs, curx) -> no acquire-inv needed anywhere in the
// main loop. Explicit vmcnt + sched_barrier discipline (guide rule #18).
__device__ __forceinline__ void ld4cv(v8s& a0, v8s& a1, v8s& a2, v8s& a3,
                                      const u16* p0, const u16* p1,
                                      const u16* p2, const u16* p3) {
  asm volatile(
      "global_load_dwordx4 %0, %4, off sc0 sc1\n\t"
      "global_load_dwordx4 %1, %5, off sc0 sc1\n\t"
      "global_load_dwordx4 %2, %6, off sc0 sc1\n\t"
      "global_load_dwordx4 %3, %7, off sc0 sc1"
      : "=&v"(a0), "=&v"(a1), "=&v"(a2), "=&v"(a3)
      : "v"(p0), "v"(p1), "v"(p2), "v"(p3)
      : "memory");
}
#define WAITV(N) do { asm volatile("s_waitcnt vmcnt(" #N ")" ::: "memory"); \
                      __builtin_amdgcn_sched_barrier(0); } while (0)
#define MFMA8(A, W, I, ACC) do { \
  _Pragma("unroll") \
  for (int mt_ = 0; mt_ < 4; ++mt_) { \
    ACC[0][mt_] = __builtin_amdgcn_mfma_f32_16x16x32_bf16(A[mt_], W[0][I], ACC[0][mt_], 0, 0, 0); \
    ACC[1][mt_] = __builtin_amdgcn_mfma_f32_16x16x32_bf16(A[mt_], W[1][I], ACC[1][mt_], 0, 0, 0); \
  } } while (0)

struct Params {
  const float *x, *h0, *c0;
  const float *Wi0, *Wh0, *bi0, *bh0;
  const float *Wi1, *Wh1, *bi1, *bh1;
  const float *Wi2, *Wh2, *bi2, *bh2;
  const float *Wfc, *bfc;
  float *out;
  u16 *wb0i, *wb0h, *wb1i, *wb1h, *wb2i, *wb2h, *wbfc;
  u16 *xb, *hA, *hB, *curx;
  float *b0, *b1, *b2, *bfcs;
  unsigned *bflags;  // f0[128] | f1[128] | f2[128] | xflag[32] lines (x32 words)
  int P, T;
};

// ---------------- init: fp32 -> bf16 conversions, bias sums, state init ----
__global__ void init_kernel(Params p) {
  long gid = (long)blockIdx.x * blockDim.x + threadIdx.x;
  long stride = (long)gridDim.x * blockDim.x;
  const long nw0i = 4096L * kD, nwh = 4096L * kH, nfc = (long)kD * kH;
  for (long i = gid; i < nw0i; i += stride) p.wb0i[i] = f2b(p.Wi0[i]);
  for (long i = gid; i < nwh; i += stride) {
    p.wb0h[i] = f2b(p.Wh0[i]);
    p.wb1i[i] = f2b(p.Wi1[i]);
    p.wb1h[i] = f2b(p.Wh1[i]);
    p.wb2i[i] = f2b(p.Wi2[i]);
    p.wb2h[i] = f2b(p.Wh2[i]);
  }
  for (long i = gid; i < nfc; i += stride) p.wbfc[i] = f2b(p.Wfc[i]);
  for (long i = gid; i < 4096; i += stride) {
    p.b0[i] = p.bi0[i] + p.bh0[i];
    p.b1[i] = p.bi1[i] + p.bh1[i];
    p.b2[i] = p.bi2[i] + p.bh2[i];
  }
  for (long i = gid; i < kD; i += stride) p.bfcs[i] = p.bfc[i];
  for (long i = gid; i < NFLAG; i += stride) p.bflags[i] = 0u;  // flag state
  long nx = (long)p.P * kB * kD;
  for (long i = gid; i < nx; i += stride) {
    p.xb[i] = f2b(p.x[i]);
    p.out[i] = p.x[i];  // teacher-forced rows are exact copies
  }
  long nh = (long)kL * kB * kH;
  for (long i = gid; i < nh; i += stride) p.hA[i] = f2b(p.h0[i]);
}

// ---------------- persistent RNN: wave-level dataflow, dedicated FC ----
// Round-7: (a) FC moved to 8 DEDICATED blocks (bid>=128): K-split-2 across
// wave pairs (16-MFMA chain + LDS pair-reduce), bypass h2 loads (no inv ->
// Wfc stays cached), 64-producer-flag polls per wave. LSTM phase A is now
// uniform across all 128 blocks (no f0 lateness). (b) launch_bounds(512,2)
// -> 256-VGPR budget (1 block/CU anyway): weights live in registers.
// (c) single-sync epilogue (doubled LDS) + wave-local coalesced h publish.
// Certification chains unchanged from round 6 (per-wave, set = 16 blocks):
//   A(t) h0(t-1): this wave's B(t-1) poll of f0(t-1).
//   B(t) h1(t-1): C(t-1) poll of f1(t-1).
//   C(t) h2(t-1): B(t) poll of f0(t).
//   A(t) curx(t): xflag poll (8 producer FC wave-tiles).
//   FC(t) h2(t-1): direct poll of its 64 K-half producers' f2 >= t.
// WAR: FC(t) overwrites curx(t-1) only after f2 >= t, which postdates every
// block's A(t-1); h slabs as in round 6.
__global__ void __launch_bounds__(NTHR, 2) rnn_kernel(Params p) {
  const int tid = threadIdx.x, bid = blockIdx.x;
  const int lane = tid & 63, w = tid >> 6;  // 8 waves
  const int colc = lane & 15, kq = lane >> 4;
  const int aoff = kq * 8;
  unsigned* f0arr = p.bflags;
  unsigned* f1arr = p.bflags + NBLK * 32;
  unsigned* f2arr = p.bflags + 2 * NBLK * 32;
  unsigned* xflag = p.bflags + 3 * NBLK * 32;  // 32 lines, one per FC tile
  const int T = p.T, P = p.P;
  const f32x4 z4 = {0.f, 0.f, 0.f, 0.f};

  // ================= dedicated FC blocks =================
  if (bid >= NBLK) {
    if (T - 1 <= P) return;
    __shared__ float fcred[4][64][4];
    const int fbid = bid - NBLK;     // 0..7: owns d-cols [fbid*16, fbid*16+16)
    const int wm = w & 3;            // m-tile (batch rows wm*16..+15)
    const int half = w >> 2;         // K half (0: units 0-511, 1: 512-1023)
    const u16* bp = p.wbfc + (long)(fbid * 16 + colc) * kH + half * 512 + aoff;
    const float bv = p.bfcs[fbid * 16 + colc];
    for (int t = P; t < T - 1; ++t) {
      const u16* hOld = (t & 1) ? p.hB : p.hA;  // h2(t-1) slab
      {  // poll this K-half's 64 producer blocks: f2 >= t
        const unsigned tgt = (unsigned)t;
        unsigned* fp = f2arr + (half * 64 + lane) * 32;
        for (;;) {
          unsigned v = __hip_atomic_load(fp, __ATOMIC_RELAXED, __HIP_MEMORY_SCOPE_AGENT);
          if (__all((int)(v >= tgt))) break;
          __builtin_amdgcn_s_sleep(1);
        }
        asm volatile("" ::: "memory");
      }
      const u16* ap = hOld + 2L * kB * kH + (long)(wm * 16 + colc) * kH + half * 512 + aoff;
      f32x4 u = z4;
      v8s A0[4], A1[4];
      ld4cv(A0[0], A0[1], A0[2], A0[3], ap, ap + 32, ap + 64, ap + 96);
      ld4cv(A1[0], A1[1], A1[2], A1[3], ap + 128, ap + 160, ap + 192, ap + 224);
      WAITV(4);
#pragma unroll
      for (int j = 0; j < 4; ++j)
        u = __builtin_amdgcn_mfma_f32_16x16x32_bf16(A0[j], *(const v8s*)(bp + j * 32), u, 0, 0, 0);
      ld4cv(A0[0], A0[1], A0[2], A0[3], ap + 256, ap + 288, ap + 320, ap + 352);
      WAITV(4);
#pragma unroll
      for (int j = 0; j < 4; ++j)
        u = __builtin_amdgcn_mfma_f32_16x16x32_bf16(A1[j], *(const v8s*)(bp + (4 + j) * 32), u, 0, 0, 0);
      ld4cv(A1[0], A1[1], A1[2], A1[3], ap + 384, ap + 416, ap + 448, ap + 480);
      WAITV(4);
#pragma unroll
      for (int j = 0; j < 4; ++j)
        u = __builtin_amdgcn_mfma_f32_16x16x32_bf16(A0[j], *(const v8s*)(bp + (8 + j) * 32), u, 0, 0, 0);
      WAITV(0);
#pragma unroll
      for (int j = 0; j < 4; ++j)
        u = __builtin_amdgcn_mfma_f32_16x16x32_bf16(A1[j], *(const v8s*)(bp + (12 + j) * 32), u, 0, 0, 0);
      // K-half pair reduce via LDS; half 0 finalizes + publishes
      if (half) *(f32x4*)&fcred[wm][lane][0] = u;
      __syncthreads();
      if (!half) {
        f32x4 up = *(const f32x4*)&fcred[wm][lane][0];
        float* orow = p.out + (long)t * (kB * kD);
#pragma unroll
        for (int r = 0; r < 4; ++r) {
          float val = sigm(u[r] + up[r] + bv);
          int bb = wm * 16 + kq * 4 + r, d = fbid * 16 + colc;
          st32(orow + (long)bb * kD + d, val);
          st16(p.curx + (long)bb * kD + d, f2b(val));
        }
        asm volatile("s_waitcnt vmcnt(0)" ::: "memory");
        if (lane == 0)
          st32u(xflag + (fbid * 4 + wm) * 32, (unsigned)(t - P + 1));
      }
      __syncthreads();  // protect fcred against next-iter overwrite
    }
    return;
  }

  // ================= LSTM blocks (bid < 128) =================
  const int u7 = colc & 7, gh = colc >> 3;
  const long wr0 = (long)gh * kH + bid * 8 + u7;        // gate-rows 0/1 tile
  const long wr1 = (long)(2 + gh) * kH + bid * 8 + u7;  // gate-rows 2/3 tile

  // ---- one-time weight preload (register-resident under 256-VGPR budget) --
  v8s w0x[2];  // waves 0-3 only: L0 x k-tile w
  v8s w0h[2][4], w1x[2][4], w1h[2][4], w2x[2][4], w2h[2][4];
  if (w < 4) {
    w0x[0] = *(const v8s*)(p.wb0i + wr0 * kD + w * 32 + aoff);
    w0x[1] = *(const v8s*)(p.wb0i + wr1 * kD + w * 32 + aoff);
  }
#pragma unroll
  for (int i = 0; i < 4; ++i) {
    int k = (w + 8 * i) * 32 + aoff;
    w0h[0][i] = *(const v8s*)(p.wb0h + wr0 * kH + k);
    w0h[1][i] = *(const v8s*)(p.wb0h + wr1 * kH + k);
    w1x[0][i] = *(const v8s*)(p.wb1i + wr0 * kH + k);
    w1x[1][i] = *(const v8s*)(p.wb1i + wr1 * kH + k);
    w1h[0][i] = *(const v8s*)(p.wb1h + wr0 * kH + k);
    w1h[1][i] = *(const v8s*)(p.wb1h + wr1 * kH + k);
    w2x[0][i] = *(const v8s*)(p.wb2i + wr0 * kH + k);
    w2x[1][i] = *(const v8s*)(p.wb2i + wr1 * kH + k);
    w2h[0][i] = *(const v8s*)(p.wb2h + wr0 * kH + k);
    w2h[1][i] = *(const v8s*)(p.wb2h + wr1 * kH + k);
  }

  // ---- per-thread cell state: 1 (batch, unit) cell per layer ----
  const int em = tid >> 3, eu = tid & 7;
  const int ehid = bid * 8 + eu;
  float cst[kL], brg[kL][4];
#pragma unroll
  for (int l = 0; l < kL; ++l)
    cst[l] = p.c0[(long)l * kB * kH + (long)em * kH + ehid];
  {
    const float* bp[3] = {p.b0, p.b1, p.b2};
#pragma unroll
    for (int l = 0; l < 3; ++l)
#pragma unroll
      for (int gg = 0; gg < 4; ++gg) brg[l][gg] = bp[l][gg * kH + ehid];
  }

  __shared__ float lg[2][8][64][18];  // both acc halves -> single-sync reduce
  __shared__ u16 hsh[8][64];          // per-wave h staging for coalesced publish

  auto epilogue = [&](int l, f32x4(&acc)[2][4], u16* hOut) {
#pragma unroll
    for (int hh = 0; hh < 2; ++hh)
#pragma unroll
      for (int mt = 0; mt < 4; ++mt)
#pragma unroll
        for (int r = 0; r < 4; ++r)
          lg[hh][w][mt * 16 + kq * 4 + r][colc] = acc[hh][mt][r];
    __syncthreads();
    float s0 = 0.f, s1 = 0.f, s2 = 0.f, s3 = 0.f;
#pragma unroll
    for (int ww = 0; ww < 8; ++ww) {
      s0 += lg[0][ww][em][eu];
      s1 += lg[0][ww][em][8 + eu];
      s2 += lg[1][ww][em][eu];
      s3 += lg[1][ww][em][8 + eu];
    }
    float iv = s0 + brg[l][0], fv = s1 + brg[l][1];
    float gv = s2 + brg[l][2], ov = s3 + brg[l][3];
    float cn = sigm(fv) * cst[l] + sigm(iv) * tanhf(gv);
    cst[l] = cn;
    // wave-local coalesced publish: 64xu16 -> 8 lanes x st128 (16B rows)
    hsh[w][lane] = f2b(sigm(ov) * tanhf(cn));
    asm volatile("s_waitcnt lgkmcnt(0)" ::: "memory");
    if (lane < 8) {
      v8s hv = *(const v8s*)&hsh[w][lane * 8];
      st128(hOut + (long)(w * 8 + lane) * kH + bid * 8, hv);
    }
  };

  // Arrival: per-wave drain -> block sync -> thread0 publishes layer flag.
  auto arrive = [&](unsigned* farr, unsigned val) {
    asm volatile("s_waitcnt vmcnt(0)" ::: "memory");
    __syncthreads();
    if (tid == 0) st32u(farr + bid * 32, val);
  };

  // Per-wave poll of this wave's 16 producer blocks (k-tiles {w+8i}).
  auto poll16 = [&](unsigned* farr, unsigned tgt) {
    unsigned* fp = farr + (4 * (w + 8 * (lane >> 2)) + (lane & 3)) * 32;
    for (;;) {
      unsigned v = (lane < 16)
          ? __hip_atomic_load(fp, __ATOMIC_RELAXED, __HIP_MEMORY_SCOPE_AGENT)
          : tgt;
      if (__all((int)(v >= tgt))) break;
      __builtin_amdgcn_s_sleep(1);
    }
    asm volatile("" ::: "memory");  // no loads hoisted above the poll
  };

  // Bypass-load GEMM over 4 k-tiles {w+8i}: 2-deep pipelined 4-load batches.
  auto gemm16 = [&](const u16* Ab, v8s (&W)[2][4], f32x4 (&acc)[2][4]) {
    const u16* b0 = Ab + (long)colc * kH + w * 32 + aoff;
    const u16* b1 = b0 + 16 * kH;
    const u16* b2 = b0 + 32 * kH;
    const u16* b3 = b0 + 48 * kH;
    v8s A0[4], A1[4], A2[4], A3[4];
    ld4cv(A0[0], A0[1], A0[2], A0[3], b0, b1, b2, b3);
    ld4cv(A1[0], A1[1], A1[2], A1[3], b0 + 256, b1 + 256, b2 + 256, b3 + 256);
    WAITV(4);
    MFMA8(A0, W, 0, acc);
    ld4cv(A2[0], A2[1], A2[2], A2[3], b0 + 512, b1 + 512, b2 + 512, b3 + 512);
    WAITV(4);
    MFMA8(A1, W, 1, acc);
    ld4cv(A3[0], A3[1], A3[2], A3[3], b0 + 768, b1 + 768, b2 + 768, b3 + 768);
    WAITV(4);
    MFMA8(A2, W, 2, acc);
    WAITV(0);
    MFMA8(A3, W, 3, acc);
  };

  for (int t = 0; t < T - 1; ++t) {
    const u16* hOld = (t & 1) ? p.hB : p.hA;
    u16* hNew = (t & 1) ? p.hA : p.hB;
    const bool genstep = (t >= P);
    const unsigned ft = (unsigned)(t + 1);

    // ================= phase A: L0 (uniform across all 128 blocks) =========
    {
      f32x4 acc[2][4] = {z4, z4, z4, z4, z4, z4, z4, z4};
      // h-part: wait-free (certified by this wave's B(t-1) poll of f0(t-1)).
      gemm16(hOld, w0h, acc);
      // x-part: waves 0-3, one k-tile each.
      if (w < 4) {
        if (genstep) {
          // 8 producer FC wave-tiles for d-tile w: f in {2w,2w+1} x m 0..3
          const unsigned tag = (unsigned)(t - P + 1);
          unsigned* fp = xflag + ((2 * w + (lane >> 2)) * 4 + (lane & 3)) * 32;
          for (;;) {
            unsigned v = (lane < 8)
                ? __hip_atomic_load(fp, __ATOMIC_RELAXED, __HIP_MEMORY_SCOPE_AGENT)
                : tag;
            if (__all((int)(v >= tag))) break;
            __builtin_amdgcn_s_sleep(1);
          }
          asm volatile("" ::: "memory");
          const u16* xb0 = p.curx + (long)colc * kD + w * 32 + aoff;
          v8s X[4];
          ld4cv(X[0], X[1], X[2], X[3],
                xb0, xb0 + 16 * kD, xb0 + 32 * kD, xb0 + 48 * kD);
          WAITV(0);
#pragma unroll
          for (int mt = 0; mt < 4; ++mt) {
            acc[0][mt] = __builtin_amdgcn_mfma_f32_16x16x32_bf16(X[mt], w0x[0], acc[0][mt], 0, 0, 0);
            acc[1][mt] = __builtin_amdgcn_mfma_f32_16x16x32_bf16(X[mt], w0x[1], acc[1][mt], 0, 0, 0);
          }
        } else {
          const u16* xin = p.xb + (long)t * kB * kD;
          int k = w * 32 + aoff;
#pragma unroll
          for (int mt = 0; mt < 4; ++mt) {
            v8s a = *(const v8s*)(xin + (long)(mt * 16 + colc) * kD + k);
            acc[0][mt] = __builtin_amdgcn_mfma_f32_16x16x32_bf16(a, w0x[0], acc[0][mt], 0, 0, 0);
            acc[1][mt] = __builtin_amdgcn_mfma_f32_16x16x32_bf16(a, w0x[1], acc[1][mt], 0, 0, 0);
          }
        }
      }
      epilogue(0, acc, hNew);
      arrive(f0arr, ft);
    }

    // ================= phase B: L1 =================
    {
      f32x4 acc[2][4] = {z4, z4, z4, z4, z4, z4, z4, z4};
      // h-part h1(t-1): certified by this wave's C(t-1) poll of f1(t-1).
      gemm16(hOld + (long)kB * kH, w1h, acc);
      // x-part h0(t): per-wave 16-flag wait, then bypass loads.
      poll16(f0arr, ft);
      gemm16(hNew, w1x, acc);
      epilogue(1, acc, hNew + (long)kB * kH);
      arrive(f1arr, ft);
    }

    // ================= phase C: L2 =================
    {
      f32x4 acc[2][4] = {z4, z4, z4, z4, z4, z4, z4, z4};
      // h-part h2(t-1): certified by this wave's B(t) poll of f0(t).
      gemm16(hOld + 2L * kB * kH, w2h, acc);
      // x-part h1(t): per-wave 16-flag wait.
      poll16(f1arr, ft);
      gemm16(hNew + (long)kB * kH, w2x, acc);
      epilogue(2, acc, hNew + 2L * kB * kH);
      arrive(f2arr, ft);
    }
  }

  // ===== final emitted row out[T-1]: FC from h2(T-2), block 0 only =====
  if (bid == 0 && T - 1 >= P && T >= 2) {
    const unsigned tgt = (unsigned)(T - 1);  // f2 after last C = T-1
    {
      const int i = threadIdx.x;
      unsigned* fp = f2arr + i * 32;
      for (;;) {
        unsigned v = (i < NBLK)
            ? __hip_atomic_load(fp, __ATOMIC_RELAXED, __HIP_MEMORY_SCOPE_AGENT)
            : tgt;
        if (__syncthreads_and((int)(v >= tgt))) break;
        __builtin_amdgcn_s_sleep(1);
      }
      if (tid == 0)
        (void)__hip_atomic_load(f2arr, __ATOMIC_ACQUIRE, __HIP_MEMORY_SCOPE_AGENT);
      __syncthreads();
    }
    const u16* hL = ((T - 2) & 1) ? p.hA : p.hB;  // hNew of iteration T-2
    const u16* wfc_r = p.wbfc + (long)(w * 16 + colc) * kH + aoff;
    const u16* ap = hL + 2L * kB * kH + (long)colc * kH + aoff;
    f32x4 fa[4] = {z4, z4, z4, z4};
#pragma unroll 2
    for (int kk = 0; kk < 32; ++kk) {
      v8s b = *(const v8s*)(wfc_r + kk * 32);
#pragma unroll
      for (int mt = 0; mt < 4; ++mt) {
        v8s a = *(const v8s*)(ap + mt * 16 * kH + kk * 32);
        fa[mt] = __builtin_amdgcn_mfma_f32_16x16x32_bf16(a, b, fa[mt], 0, 0, 0);
      }
    }
    float bv = p.bfcs[w * 16 + colc];
    float* orow = p.out + (long)(T - 1) * (kB * kD);
#pragma unroll
    for (int mt = 0; mt < 4; ++mt)
#pragma unroll
      for (int r = 0; r < 4; ++r) {
        int bb = mt * 16 + kq * 4 + r, d = w * 16 + colc;
        st32(orow + (long)bb * kD + d, sigm(fa[mt][r] + bv));
      }
  }
}

extern "C" void kernel_launch(void* const* d_in, const int* in_sizes, int n_in,
                              void* d_out, int out_size, void* d_ws, size_t ws_size,
                              hipStream_t stream) {
  Params p;
  p.x   = (const float*)d_in[0];
  p.h0  = (const float*)d_in[1];
  p.c0  = (const float*)d_in[2];
  p.Wi0 = (const float*)d_in[3];
  p.Wh0 = (const float*)d_in[4];
  p.bi0 = (const float*)d_in[5];
  p.bh0 = (const float*)d_in[6];
  p.Wi1 = (const float*)d_in[7];
  p.Wh1 = (const float*)d_in[8];
  p.bi1 = (const float*)d_in[9];
  p.bh1 = (const float*)d_in[10];
  p.Wi2 = (const float*)d_in[11];
  p.Wh2 = (const float*)d_in[12];
  p.bi2 = (const float*)d_in[13];
  p.bh2 = (const float*)d_in[14];
  p.Wfc = (const float*)d_in[15];
  p.bfc = (const float*)d_in[16];
  p.out = (float*)d_out;
  p.P = in_sizes[0] / (kB * kD);
  p.T = out_size / (kB * kD);

  char* w = (char*)d_ws;
  auto alloc = [&](size_t bytes) {
    char* r = w;
    w += (bytes + 255) & ~(size_t)255;
    return r;
  };
  p.wb0i = (u16*)alloc(4096L * kD * 2);
  p.wb0h = (u16*)alloc(4096L * kH * 2);
  p.wb1i = (u16*)alloc(4096L * kH * 2);
  p.wb1h = (u16*)alloc(4096L * kH * 2);
  p.wb2i = (u16*)alloc(4096L * kH * 2);
  p.wb2h = (u16*)alloc(4096L * kH * 2);
  p.wbfc = (u16*)alloc((long)kD * kH * 2);
  p.xb   = (u16*)alloc((long)p.P * kB * kD * 2);
  p.hA   = (u16*)alloc((long)kL * kB * kH * 2);
  p.hB   = (u16*)alloc((long)kL * kB * kH * 2);
  p.curx = (u16*)alloc((long)kB * kD * 2);
  p.b0   = (float*)alloc(4096 * 4);
  p.b1   = (float*)alloc(4096 * 4);
  p.b2   = (float*)alloc(4096 * 4);
  p.bfcs = (float*)alloc(kD * 4);
  p.bflags = (unsigned*)alloc(NFLAG * 4);

  hipLaunchKernelGGL(init_kernel, dim3(512), dim3(256), 0, stream, p);
  void* args[] = { &p };
  hipLaunchCooperativeKernel((const void*)rnn_kernel, dim3(NBLK_TOT), dim3(NTHR),
                             args, 0, stream);
}